// Round 5
// baseline (5332.471 us; speedup 1.0000x reference)
//
#include <hip/hip_runtime.h>
#include <stdint.h>

typedef unsigned short u16;
typedef __attribute__((ext_vector_type(8))) short short8;
typedef __attribute__((ext_vector_type(4))) float f32x4;

__device__ __forceinline__ float bf2f(u16 u) {
  union { unsigned int i; float f; } x; x.i = ((unsigned int)u) << 16; return x.f;
}
__device__ __forceinline__ u16 f2bf(float f) {
  union { float f; unsigned int i; } x; x.f = f;
  unsigned int r = x.i + 0x7fffu + ((x.i >> 16) & 1u);
  return (u16)(r >> 16);
}

typedef __attribute__((address_space(1))) const unsigned int as1_uint;
typedef __attribute__((address_space(3))) unsigned int as3_uint;

__device__ __forceinline__ void gload_lds16(const void* g, void* l) {
  __builtin_amdgcn_global_load_lds(
      (const as1_uint*)(unsigned long long)g,
      (as3_uint*)(unsigned int)(unsigned long long)l,
      16, 0, 0);
}

// inline-asm LDS read: opaque to the backend waitcnt pass.
__device__ __forceinline__ short8 dsr128(const void* p) {
  short8 r;
  asm volatile("ds_read_b128 %0, %1"
               : "=v"(r)
               : "v"((unsigned int)(unsigned long long)p));
  return r;
}

#define FENCE() asm volatile("" ::: "memory")
#define BAR() do { FENCE(); __builtin_amdgcn_s_barrier(); FENCE(); } while (0)
#define VMCNT(n) asm volatile("s_waitcnt vmcnt(" #n ")" ::: "memory")
#define LGKM0_SB() do { asm volatile("s_waitcnt lgkmcnt(0)"); __builtin_amdgcn_sched_barrier(0); } while (0)

// ---------------- transpose + fp32->bf16 convert: in (L,K,N) f32 -> out (L,N,K) bf16
// perm=2 (w12): output column 32-chunks interleave x1/x2.
__global__ __launch_bounds__(256) void transpose_conv(const float* __restrict__ in, u16* __restrict__ out,
                                                      int K, int N, int perm) {
  __shared__ float tile[32][33];
  const long l = blockIdx.z;
  int nb = blockIdx.x;
  int nbsrc = nb;
  if (perm == 2) {
    nbsrc = (nb & 1) ? 64 + (nb >> 1) : (nb >> 1);
  }
  const int nbS = nbsrc * 32;
  const int nbD = nb * 32;
  const int kb = blockIdx.y * 32;
  const float* I = in + l * (long)K * N;
  u16* O = out + l * (long)N * K;
  const int tx = threadIdx.x, ty = threadIdx.y; // (32,8)
#pragma unroll
  for (int i = 0; i < 32; i += 8)
    tile[ty + i][tx] = I[(long)(kb + ty + i) * N + nbS + tx];
  __syncthreads();
#pragma unroll
  for (int i = 0; i < 32; i += 8)
    O[(long)(nbD + ty + i) * K + kb + tx] = f2bf(tile[tx][ty + i]);
}

// ---------------- embed: z = rms(z_latents @ We + be + pos, ln_pre_w), fp32 out
__global__ __launch_bounds__(256) void embed_kernel(const float* __restrict__ zl, const float* __restrict__ pos,
                                                    const float* __restrict__ We, const float* __restrict__ be,
                                                    const float* __restrict__ lnw, float* __restrict__ z) {
  const long row = blockIdx.x;          // b*256+n
  const int n = (int)(row & 255);
  const int t = threadIdx.x;
  __shared__ float zc[16];
  __shared__ float wsum[4];
  if (t < 16) zc[t] = zl[row * 16 + t];
  __syncthreads();
  float v[3];
#pragma unroll
  for (int e = 0; e < 3; ++e) {
    const int col = t + e * 256;
    float s = be[col] + pos[(long)n * 768 + col];
#pragma unroll
    for (int c = 0; c < 16; ++c) s += zc[c] * We[c * 768 + col];
    v[e] = s;
  }
  float ss = v[0] * v[0] + v[1] * v[1] + v[2] * v[2];
#pragma unroll
  for (int off = 32; off > 0; off >>= 1) ss += __shfl_down(ss, off, 64);
  if ((t & 63) == 0) wsum[t >> 6] = ss;
  __syncthreads();
  const float tot = wsum[0] + wsum[1] + wsum[2] + wsum[3];
  const float rs = rsqrtf(tot * (1.f / 768.f) + 1e-6f);
#pragma unroll
  for (int e = 0; e < 3; ++e) {
    const int col = t + e * 256;
    z[row * 768 + col] = v[e] * rs * lnw[col];
  }
}

// ---------------- wave-parallel rms: 4 waves/block, 8 rows/wave, float4 loads.
__global__ __launch_bounds__(256) void rms_wave(const float* __restrict__ z, const float* __restrict__ w,
                                                u16* __restrict__ h) {
  const int lane = threadIdx.x & 63;
  const int wv = threadIdx.x >> 6;
  float4 wl[3];
#pragma unroll
  for (int k = 0; k < 3; ++k) wl[k] = *(const float4*)(w + k * 256 + lane * 4);
  const long base = ((long)blockIdx.x * 4 + wv) * 8;
  for (int r = 0; r < 8; ++r) {
    const long row = base + r;
    const float* zr = z + row * 768;
    float4 xv[3];
    float ss = 0.f;
#pragma unroll
    for (int k = 0; k < 3; ++k) {
      xv[k] = *(const float4*)(zr + k * 256 + lane * 4);
      ss += xv[k].x * xv[k].x + xv[k].y * xv[k].y + xv[k].z * xv[k].z + xv[k].w * xv[k].w;
    }
#pragma unroll
    for (int o = 1; o < 64; o <<= 1) ss += __shfl_xor(ss, o);
    const float rs = rsqrtf(ss * (1.f / 768.f) + 1e-6f);
    u16* hr = h + row * 768;
#pragma unroll
    for (int k = 0; k < 3; ++k) {
      uint2 pk;
      pk.x = (unsigned int)f2bf(xv[k].x * rs * wl[k].x) | ((unsigned int)f2bf(xv[k].y * rs * wl[k].y) << 16);
      pk.y = (unsigned int)f2bf(xv[k].z * rs * wl[k].z) | ((unsigned int)f2bf(xv[k].w * rs * wl[k].w) << 16);
      *(uint2*)(hr + k * 256 + lane * 4) = pk;
    }
  }
}

// ---------------- 128x128 GEMM, SINGLE-buffered, 48KB LDS pad -> 3 blocks/CU (proven optimum).
// Kept for N=768 GEMMs (proj/w3/c1): 256-tile would leave 64 CUs idle there.
template <int OUT_MODE>
__global__ __launch_bounds__(256, 3) void gemm128s(const u16* __restrict__ A, const u16* __restrict__ Bt,
                                                   void* __restrict__ C, const float* __restrict__ bias,
                                                   int M, int N, int K, int nbn, int super,
                                                   const float* __restrict__ rope, u16* __restrict__ q_r,
                                                   u16* __restrict__ k_s, u16* __restrict__ v_t) {
  __shared__ __align__(16) char ldsc[49152];  // 32KB used (A@0, B@16384); +16KB pad -> 3 blocks/CU
  const int tid = threadIdx.x;
  const int lane = tid & 63;
  const int wave = tid >> 6;
  const int i = lane & 15, g = lane >> 4;
  const int wr = wave >> 1, wc = wave & 1;
  const int xsw = (i & 7) << 4;

  const int wg = blockIdx.x, nwg = gridDim.x;
  const int w2 = (wg & 7) * (nwg >> 3) + (wg >> 3);
  int bm, bn;
  if (super == 8) {
    const int s = w2 >> 6, t = w2 & 63;
    const int scols = nbn >> 3;
    bm = ((s / scols) << 3) + (t >> 3);
    bn = ((s % scols) << 3) + (t & 7);
  } else if (super == 6) {
    const int s = w2 / 48, t = w2 % 48;
    const int scols = nbn / 6;
    bm = ((s / scols) << 3) + t / 6;
    bn = (s % scols) * 6 + t % 6;
  } else {
    bm = w2 / nbn; bn = w2 - bm * nbn;
  }
  const long m0 = (long)bm * 128, n0 = (long)bn * 128;

  const u16* Ab_ = A + m0 * K;
  const u16* Bb_ = Bt + n0 * K;
  const int srow = tid >> 3;
  const int scol = ((((tid & 7) * 16) ^ ((srow & 7) << 4)) >> 1);
  const int NT = K >> 6;

  auto stageA = [&](int kk) {
    const u16* s_ = Ab_ + (long)srow * K + kk + scol;
    char* d = ldsc + wave * 1024;
    gload_lds16(s_, d);
    gload_lds16(s_ + 32L * K, d + 4096);
    gload_lds16(s_ + 64L * K, d + 8192);
    gload_lds16(s_ + 96L * K, d + 12288);
  };
  auto stageB = [&](int kk) {
    const u16* s_ = Bb_ + (long)srow * K + kk + scol;
    char* d = ldsc + 16384 + wave * 1024;
    gload_lds16(s_, d);
    gload_lds16(s_ + 32L * K, d + 4096);
    gload_lds16(s_ + 64L * K, d + 8192);
    gload_lds16(s_ + 96L * K, d + 12288);
  };

  f32x4 acc[4][4];
#pragma unroll
  for (int mf = 0; mf < 4; ++mf)
#pragma unroll
    for (int nf = 0; nf < 4; ++nf) { f32x4 zz = {0.f, 0.f, 0.f, 0.f}; acc[mf][nf] = zz; }
  short8 af[4][2], bf[4][2];
  const char* Abuf = ldsc;
  const char* Bbuf = ldsc + 16384;

#define LOAD_A()                                                                                 \
  _Pragma("unroll") for (int r = 0; r < 4; ++r) _Pragma("unroll") for (int s2 = 0; s2 < 2; ++s2) \
      af[r][s2] = dsr128(Abuf + (wr * 64 + r * 16 + i) * 128 + ((s2 * 64 + g * 16) ^ xsw));
#define LOAD_B()                                                                                 \
  _Pragma("unroll") for (int q = 0; q < 4; ++q) _Pragma("unroll") for (int s2 = 0; s2 < 2; ++s2) \
      bf[q][s2] = dsr128(Bbuf + (wc * 64 + q * 16 + i) * 128 + ((s2 * 64 + g * 16) ^ xsw));
#define MFMA_ALL()                                                                               \
  do {                                                                                           \
    __builtin_amdgcn_s_setprio(1);                                                               \
    _Pragma("unroll") for (int r = 0; r < 4; ++r)                                                \
    _Pragma("unroll") for (int q = 0; q < 4; ++q)                                                \
    _Pragma("unroll") for (int s2 = 0; s2 < 2; ++s2)                                             \
        acc[r][q] = __builtin_amdgcn_mfma_f32_16x16x32_bf16(af[r][s2], bf[q][s2], acc[r][q],     \
                                                            0, 0, 0);                            \
    __builtin_amdgcn_s_setprio(0);                                                               \
  } while (0)

  stageA(0); stageB(0);
  VMCNT(0);
  BAR();

  for (int t2 = 0; t2 < NT; ++t2) {
    const bool pf = (t2 + 1 < NT);
    const int k1 = (t2 + 1) * 64;
    LOAD_A(); LOAD_B();
    LGKM0_SB();
    BAR();
    if (pf) { stageA(k1); stageB(k1); }
    MFMA_ALL();
    if (pf) VMCNT(0);
    BAR();
  }
#undef LOAD_A
#undef LOAD_B
#undef MFMA_ALL

  if constexpr (OUT_MODE == 3) {
    u16* U = (u16*)C;
#pragma unroll
    for (int mf = 0; mf < 4; ++mf) {
      const long rowb = m0 + wr * 64 + mf * 16 + g * 4;
#pragma unroll
      for (int nf2 = 0; nf2 < 2; ++nf2) {
        const int col = bn * 64 + wc * 32 + nf2 * 16 + i;
        const float bv1 = bias[col];
        const float bv2 = bias[2048 + col];
#pragma unroll
        for (int j = 0; j < 4; ++j) {
          const float x1 = acc[mf][nf2][j] + bv1;
          const float x2 = acc[mf][nf2 + 2][j] + bv2;
          const float uu = x1 / (1.f + __expf(-x1)) * x2;
          U[(rowb + j) * 2048 + col] = f2bf(uu);
        }
      }
    }
    return;
  }

  if constexpr (OUT_MODE == 4) {
    const int sec = (int)(n0 / 768);
    const int head = ((int)(n0 % 768) >> 6) + wc;
    if (sec == 2) {
#pragma unroll
      for (int mf = 0; mf < 4; ++mf) {
        const long rowb = m0 + wr * 64 + mf * 16 + g * 4;
        const int n = (int)(rowb & 255);
        const long b = rowb >> 8;
        const long bh = b * 12 + head;
        char* vp = (char*)v_t + bh * 32768;
#pragma unroll
        for (int nf = 0; nf < 4; ++nf) {
          const int d = nf * 16 + i;
          const float bv = bias[n0 + wc * 64 + d];
          uint2 pk;
          pk.x = (unsigned int)f2bf(acc[mf][nf][0] + bv) | ((unsigned int)f2bf(acc[mf][nf][1] + bv) << 16);
          pk.y = (unsigned int)f2bf(acc[mf][nf][2] + bv) | ((unsigned int)f2bf(acc[mf][nf][3] + bv) << 16);
          *(uint2*)(vp + d * 512 + ((2 * n) ^ ((d & 7) << 4))) = pk;
        }
      }
    } else {
#pragma unroll
      for (int mf = 0; mf < 4; ++mf) {
        const long rowb = m0 + wr * 64 + mf * 16 + g * 4;
#pragma unroll
        for (int nf = 0; nf < 4; ++nf) {
          const int d = nf * 16 + i;
          const float bv = bias[n0 + wc * 64 + d];
#pragma unroll
          for (int j = 0; j < 4; ++j) {
            const long row = rowb + j;
            const int n = (int)(row & 255);
            const long b = row >> 8;
            const long bh = b * 12 + head;
            const float x = acc[mf][nf][j] + bv;
            const float px = __shfl_xor(x, 1);
            const float cs = rope[n * 128 + d];
            const float sn = rope[n * 128 + 64 + d];
            const float outv = (d & 1) ? x * cs + px * sn : x * cs - px * sn;
            if (sec == 0) {
              q_r[bh * 16384 + (long)n * 64 + d] = f2bf(outv);
            } else {
              char* kp = (char*)k_s + bh * 32768;
              *(u16*)(kp + n * 128 + ((2 * d) ^ ((n & 7) << 4))) = f2bf(outv);
            }
          }
        }
      }
    }
    return;
  }

#pragma unroll
  for (int mf = 0; mf < 4; ++mf) {
    const long row = m0 + wr * 64 + mf * 16 + g * 4;
#pragma unroll
    for (int nf = 0; nf < 4; ++nf) {
      const long col = n0 + wc * 64 + nf * 16 + i;
      const float bv = bias ? bias[col] : 0.f;
#pragma unroll
      for (int j = 0; j < 4; ++j) {
        const float v = acc[mf][nf][j] + bv;
        if constexpr (OUT_MODE == 0) ((float*)C)[(row + j) * N + col] = v;
        else ((float*)C)[(row + j) * N + col] += v;
      }
    }
  }
}

// ---------------- 256x256 GEMM, derived-waits v2 (deep pipeline).
// 8 waves (2M x 4N), BK=64, 128KB LDS double-buffered. Per K-tile t, 4 phases:
//   p0 {read af(MH0)+b0f; BAR; lgkm0; MFMA Q(0,0); BAR}
//   p1 {read b1f;          BAR; lgkm0; MFMA Q(0,2); BAR}
//   p2 {read af(MH1); stage B(t+2) [B last read p1]; BAR; lgkm0; MFMA Q(4,2); BAR}
//   p3 {stage A(t+2) [A last read p2]; vmcnt(8); BAR; MFMA Q(4,0); BAR}
// All stages target t+2 (same buffer parity as t); vmcnt(8) only ever waits on
// t-1's stages, which are 4-5 phases (~2000+ cy) old -> ~zero steady-state stall.
// Safety: each phase's lgkm0 precedes its end-BAR, so a region's readers are fully
// drained before any wave can issue the overwriting DMA in a later phase.
// Prologue stages tiles 0 AND 1 fully; vmcnt(8) -> tile0 resident.
template <int OUT_MODE>
__global__ __launch_bounds__(512, 2) void gemm256(const u16* __restrict__ A, const u16* __restrict__ Bt,
                                                  void* __restrict__ C, const float* __restrict__ bias,
                                                  int N, int K, int nbn,
                                                  const float* __restrict__ rope, u16* __restrict__ q_r,
                                                  u16* __restrict__ k_s, u16* __restrict__ v_t) {
  __shared__ __align__(16) char ldsc[131072];  // A buf0@0, A buf1@32768, B buf0@65536, B buf1@98304
  const int tid = threadIdx.x;
  const int lane = tid & 63;
  const int wave = tid >> 6;           // 0..7
  const int i = lane & 15, g = lane >> 4;
  const int wr = wave >> 2, wc = wave & 3;
  const int xsw = (i & 7) << 4;

  const int wg = blockIdx.x, nwg = gridDim.x;  // nwg % 8 == 0 at all call sites
  const int w2 = (wg & 7) * (nwg >> 3) + (wg >> 3);
  const int bm = w2 / nbn, bn = w2 - bm * nbn;
  const long m0 = (long)bm * 256, n0 = (long)bn * 256;

  const u16* Ab_ = A + m0 * K;
  const u16* Bb_ = Bt + n0 * K;
  const int srow = tid >> 3;           // 0..63
  const int scol = ((((tid & 7) * 16) ^ ((srow & 7) << 4)) >> 1);  // pre-swizzled source col
  const int NT = K >> 6;

  auto stageA = [&](int t, int h) {  // half h (128 rows) of A-tile t -> buf (t&1)
    const u16* s_ = Ab_ + (long)(h * 128 + srow) * K + t * 64 + scol;
    char* d = ldsc + (t & 1) * 32768 + h * 16384 + wave * 1024;
    gload_lds16(s_, d);
    gload_lds16(s_ + 64L * K, d + 8192);
  };
  auto stageB = [&](int t, int h) {  // half h (128 rows) of B-tile t -> buf (t&1)
    const u16* s_ = Bb_ + (long)(h * 128 + srow) * K + t * 64 + scol;
    char* d = ldsc + 65536 + (t & 1) * 32768 + h * 16384 + wave * 1024;
    gload_lds16(s_, d);
    gload_lds16(s_ + 64L * K, d + 8192);
  };

  f32x4 acc[8][4];
#pragma unroll
  for (int mf = 0; mf < 8; ++mf)
#pragma unroll
    for (int nf = 0; nf < 4; ++nf) { f32x4 zz = {0.f, 0.f, 0.f, 0.f}; acc[mf][nf] = zz; }
  short8 af[4][2], b0f[2][2], b1f[2][2];

#define LOAD_A(MH)                                                                                \
  _Pragma("unroll") for (int r = 0; r < 4; ++r) _Pragma("unroll") for (int s2 = 0; s2 < 2; ++s2)  \
      af[r][s2] = dsr128(Ab + (wr * 128 + (MH) * 64 + r * 16 + i) * 128 + ((s2 * 64 + g * 16) ^ xsw));
#define LOAD_B(NH, BF)                                                                            \
  _Pragma("unroll") for (int q = 0; q < 2; ++q) _Pragma("unroll") for (int s2 = 0; s2 < 2; ++s2)  \
      BF[q][s2] = dsr128(Bb + (wc * 64 + (NH) * 32 + q * 16 + i) * 128 + ((s2 * 64 + g * 16) ^ xsw));
#define MFMA_Q(MB, NB, BF)                                                                        \
  do {                                                                                            \
    __builtin_amdgcn_s_setprio(1);                                                                \
    _Pragma("unroll") for (int r = 0; r < 4; ++r)                                                 \
    _Pragma("unroll") for (int q = 0; q < 2; ++q)                                                 \
    _Pragma("unroll") for (int s2 = 0; s2 < 2; ++s2)                                              \
        acc[(MB) + r][(NB) + q] = __builtin_amdgcn_mfma_f32_16x16x32_bf16(                        \
            af[r][s2], BF[q][s2], acc[(MB) + r][(NB) + q], 0, 0, 0);                              \
    __builtin_amdgcn_s_setprio(0);                                                                \
  } while (0)

  // prologue: tiles 0 and 1 fully staged (16 loads); vmcnt(8) -> tile0 resident.
  stageA(0, 0); stageA(0, 1); stageB(0, 0); stageB(0, 1);
  if (NT > 1) { stageA(1, 0); stageA(1, 1); stageB(1, 0); stageB(1, 1); }
  VMCNT(8);
  BAR();

  for (int t = 0; t < NT; ++t) {
    const char* Ab = ldsc + (t & 1) * 32768;
    const char* Bb = ldsc + 65536 + (t & 1) * 32768;
    const bool p2ok = (t + 2 < NT);
    // ---- phase 0
    LOAD_A(0); LOAD_B(0, b0f);
    BAR();
    LGKM0_SB();
    MFMA_Q(0, 0, b0f);
    BAR();
    // ---- phase 1
    LOAD_B(1, b1f);
    BAR();
    LGKM0_SB();
    MFMA_Q(0, 2, b1f);
    BAR();
    // ---- phase 2: stage B(t+2) (B slots last read at p1)
    LOAD_A(1);
    if (p2ok) { stageB(t + 2, 0); stageB(t + 2, 1); }
    BAR();
    LGKM0_SB();
    MFMA_Q(4, 2, b1f);
    BAR();
    // ---- phase 3: stage A(t+2) (A slots last read at p2); counted wait on t-1's stages
    if (p2ok) {
      stageA(t + 2, 0); stageA(t + 2, 1);
      VMCNT(8);
    } else {
      VMCNT(0);
    }
    BAR();
    MFMA_Q(4, 0, b0f);
    BAR();
  }
#undef LOAD_A
#undef LOAD_B
#undef MFMA_Q

  if constexpr (OUT_MODE == 3) {
    // fused swiglu (32-granular perm): acc nf 0,1 = x1, nf 2,3 = x2 for same output cols.
    u16* U = (u16*)C;
#pragma unroll
    for (int mf = 0; mf < 8; ++mf) {
      const long rowb = m0 + wr * 128 + (mf >> 2) * 64 + (mf & 3) * 16 + g * 4;
#pragma unroll
      for (int nf2 = 0; nf2 < 2; ++nf2) {
        const int col = (int)(n0 >> 1) + wc * 32 + nf2 * 16 + i;
        const float bv1 = bias[col];
        const float bv2 = bias[2048 + col];
#pragma unroll
        for (int j = 0; j < 4; ++j) {
          const float x1 = acc[mf][nf2][j] + bv1;
          const float x2 = acc[mf][nf2 + 2][j] + bv2;
          const float uu = x1 / (1.f + __expf(-x1)) * x2;
          U[(rowb + j) * 2048 + col] = f2bf(uu);
        }
      }
    }
    return;
  }

  if constexpr (OUT_MODE == 4) {
    // fused qkv epilogue: 256-col panels align with q/k/v (768 = 3*256); wave = one head.
    const int sec = (int)(n0 / 768);              // 0=q 1=k 2=v
    const int head = ((int)(n0 % 768) >> 6) + wc; // wave-uniform
    if (sec == 2) {
#pragma unroll
      for (int mf = 0; mf < 8; ++mf) {
        const long rowb = m0 + wr * 128 + (mf >> 2) * 64 + (mf & 3) * 16 + g * 4;
        const int n = (int)(rowb & 255);
        const long b = rowb >> 8;
        char* vp = (char*)v_t + (b * 12 + head) * 32768;
#pragma unroll
        for (int nf = 0; nf < 4; ++nf) {
          const int d = (nf >> 1) * 32 + (nf & 1) * 16 + i;
          const float bv = bias[n0 + wc * 64 + d];
          uint2 pk;
          pk.x = (unsigned int)f2bf(acc[mf][nf][0] + bv) | ((unsigned int)f2bf(acc[mf][nf][1] + bv) << 16);
          pk.y = (unsigned int)f2bf(acc[mf][nf][2] + bv) | ((unsigned int)f2bf(acc[mf][nf][3] + bv) << 16);
          *(uint2*)(vp + d * 512 + ((2 * n) ^ ((d & 7) << 4))) = pk;
        }
      }
    } else {
#pragma unroll
      for (int mf = 0; mf < 8; ++mf) {
        const long rowb = m0 + wr * 128 + (mf >> 2) * 64 + (mf & 3) * 16 + g * 4;
#pragma unroll
        for (int nf = 0; nf < 4; ++nf) {
          const int d = (nf >> 1) * 32 + (nf & 1) * 16 + i;
          const float bv = bias[n0 + wc * 64 + d];
#pragma unroll
          for (int j = 0; j < 4; ++j) {
            const long row = rowb + j;
            const int n = (int)(row & 255);
            const long b = row >> 8;
            const long bh = b * 12 + head;
            const float x = acc[mf][nf][j] + bv;
            const float px = __shfl_xor(x, 1);
            const float cs = rope[n * 128 + d];
            const float sn = rope[n * 128 + 64 + d];
            const float outv = (d & 1) ? x * cs + px * sn : x * cs - px * sn;
            if (sec == 0) {
              q_r[bh * 16384 + (long)n * 64 + d] = f2bf(outv);
            } else {
              char* kp = (char*)k_s + bh * 32768;
              *(u16*)(kp + n * 128 + ((2 * d) ^ ((n & 7) << 4))) = f2bf(outv);
            }
          }
        }
      }
    }
    return;
  }

#pragma unroll
  for (int mf = 0; mf < 8; ++mf) {
    const long row = m0 + wr * 128 + (mf >> 2) * 64 + (mf & 3) * 16 + g * 4;
#pragma unroll
    for (int nf = 0; nf < 4; ++nf) {
      const long col = n0 + wc * 64 + (nf >> 1) * 32 + (nf & 1) * 16 + i;
      const float bv = bias ? bias[col] : 0.f;
#pragma unroll
      for (int j = 0; j < 4; ++j) {
        const float v = acc[mf][nf][j] + bv;
        if constexpr (OUT_MODE == 0) ((float*)C)[(row + j) * N + col] = v;
        else ((float*)C)[(row + j) * N + col] += v;
      }
    }
  }
}

// ---------------- MFMA attention: block = (b,h); 4 waves x 64 query rows; N=256, D=64.
__global__ __launch_bounds__(256) void attn_kernel(const u16* __restrict__ q_r, const u16* __restrict__ k_s,
                                                   const u16* __restrict__ v_t, u16* __restrict__ out) {
  __shared__ __align__(16) u16 Kl[16384];
  __shared__ __align__(16) u16 VTl[16384];
  __shared__ __align__(16) u16 Pl[8192];
  const int tid = threadIdx.x;
  const int lane = tid & 63;
  const int w = tid >> 6;
  const int i = lane & 15;
  const int g = lane >> 4;
  const long bh = blockIdx.x;
  const u16* kg = k_s + bh * 16384;
  const u16* vg = v_t + bh * 16384;
#pragma unroll
  for (int p = 0; p < 8; ++p) {
    gload_lds16(kg + p * 2048 + tid * 8, &Kl[p * 2048 + w * 512]);
    gload_lds16(vg + p * 2048 + tid * 8, &VTl[p * 2048 + w * 512]);
  }
  __syncthreads();

  short8 qv[4][2];
  const u16* qbase = q_r + bh * 16384;
#pragma unroll
  for (int qf = 0; qf < 4; ++qf) {
#pragma unroll
    for (int kc = 0; kc < 2; ++kc)
      qv[qf][kc] = *(const short8*)(qbase + (w * 64 + qf * 16 + i) * 64 + kc * 32 + g * 8);
  }

  f32x4 o[4][4];
#pragma unroll
  for (int df = 0; df < 4; ++df)
#pragma unroll
    for (int qf = 0; qf < 4; ++qf) { f32x4 zz = {0.f, 0.f, 0.f, 0.f}; o[df][qf] = zz; }
  float m[4], l[4];
#pragma unroll
  for (int qf = 0; qf < 4; ++qf) { m[qf] = -1e30f; l[qf] = 0.f; }

  char* pw = (char*)Pl + w * 4096;

  for (int c = 0; c < 8; ++c) {
    f32x4 st[2][4];
#pragma unroll
    for (int f = 0; f < 2; ++f)
#pragma unroll
      for (int qf = 0; qf < 4; ++qf) { f32x4 zz = {0.f, 0.f, 0.f, 0.f}; st[f][qf] = zz; }
    __builtin_amdgcn_s_setprio(1);
#pragma unroll
    for (int f = 0; f < 2; ++f) {
      const int kv = c * 32 + f * 16 + i;
#pragma unroll
      for (int kc = 0; kc < 2; ++kc) {
        short8 kf = *(const short8*)((const char*)Kl + kv * 128 + (((kc * 64 + g * 16)) ^ ((kv & 7) << 4)));
#pragma unroll
        for (int qf = 0; qf < 4; ++qf)
          st[f][qf] = __builtin_amdgcn_mfma_f32_16x16x32_bf16(kf, qv[qf][kc], st[f][qf], 0, 0, 0);
      }
    }
    __builtin_amdgcn_s_setprio(0);
#pragma unroll
    for (int qf = 0; qf < 4; ++qf) {
      float s[8];
#pragma unroll
      for (int f = 0; f < 2; ++f)
#pragma unroll
        for (int j = 0; j < 4; ++j) s[f * 4 + j] = st[f][qf][j] * 0.125f;
      float cm = fmaxf(fmaxf(fmaxf(s[0], s[1]), fmaxf(s[2], s[3])),
                       fmaxf(fmaxf(s[4], s[5]), fmaxf(s[6], s[7])));
      cm = fmaxf(cm, __shfl_xor(cm, 16));
      cm = fmaxf(cm, __shfl_xor(cm, 32));
      const bool upd = cm > m[qf] + 8.f;  // defer-max (T13)
      const float newm = upd ? cm : m[qf];
      const float fac = __expf(m[qf] - newm);
      float psum = 0.f;
      u16 pb[8];
#pragma unroll
      for (int t2 = 0; t2 < 8; ++t2) {
        const float p = __expf(s[t2] - newm);
        psum += p;
        pb[t2] = f2bf(p);
      }
      l[qf] = l[qf] * fac + psum;
      m[qf] = newm;
      if (__any(upd)) {
#pragma unroll
        for (int df = 0; df < 4; ++df)
#pragma unroll
          for (int j = 0; j < 4; ++j) o[df][qf][j] *= fac;
      }
      char* pbase = pw + (qf * 16 + i) * 64 + g * 8;
      uint2 w0, w1;
      w0.x = (unsigned int)pb[0] | ((unsigned int)pb[1] << 16);
      w0.y = (unsigned int)pb[2] | ((unsigned int)pb[3] << 16);
      w1.x = (unsigned int)pb[4] | ((unsigned int)pb[5] << 16);
      w1.y = (unsigned int)pb[6] | ((unsigned int)pb[7] << 16);
      *(uint2*)(pbase) = w0;
      *(uint2*)(pbase + 32) = w1;
    }
    short8 pf[4];
#pragma unroll
    for (int qf = 0; qf < 4; ++qf)
      pf[qf] = *(const short8*)(pw + (qf * 16 + i) * 64 + g * 16);
    __builtin_amdgcn_s_setprio(1);
#pragma unroll
    for (int df = 0; df < 4; ++df) {
      const int d = df * 16 + i;
      short8 vf = *(const short8*)((const char*)VTl + d * 512 + ((c * 64 + g * 16) ^ ((d & 7) << 4)));
#pragma unroll
      for (int qf = 0; qf < 4; ++qf)
        o[df][qf] = __builtin_amdgcn_mfma_f32_16x16x32_bf16(vf, pf[qf], o[df][qf], 0, 0, 0);
    }
    __builtin_amdgcn_s_setprio(0);
  }

#pragma unroll
  for (int qf = 0; qf < 4; ++qf) {
    l[qf] += __shfl_xor(l[qf], 16);
    l[qf] += __shfl_xor(l[qf], 32);
  }

  const long b = bh / 12;
  const int hh = (int)(bh % 12);
#pragma unroll
  for (int qf = 0; qf < 4; ++qf) {
    const float inv = 1.f / l[qf];
    const long q = w * 64 + qf * 16 + i;
    u16* op = out + (b * 256 + q) * 768 + hh * 64;
#pragma unroll
    for (int df = 0; df < 4; ++df) {
      const int d0 = df * 16 + g * 4;
      unsigned int a = (unsigned int)f2bf(o[df][qf][0] * inv) | ((unsigned int)f2bf(o[df][qf][1] * inv) << 16);
      unsigned int bb = (unsigned int)f2bf(o[df][qf][2] * inv) | ((unsigned int)f2bf(o[df][qf][3] * inv) << 16);
      *(unsigned int*)(op + d0) = a;
      *(unsigned int*)(op + d0 + 2) = bb;
    }
  }
}

// ---------------- pixel shuffle + 3x3 SAME conv + bias, LDS-tiled.
__global__ __launch_bounds__(256) void conv_out_kernel(const float* __restrict__ y, const float* __restrict__ w,
                                                       const float* __restrict__ cb, float* __restrict__ out) {
  __shared__ float buf[18 * 258 * 3];
  __shared__ float wl[81];
  __shared__ float cbl[3];
  const int tid = threadIdx.x;
  const int gh = blockIdx.x;
  const long b = blockIdx.y;
  for (int idx = tid; idx < 18 * 258 * 3; idx += 256) buf[idx] = 0.f;
  if (tid < 81) wl[tid] = w[tid];
  if (tid < 3) cbl[tid] = cb[tid];
  __syncthreads();
  const float* yb = y + (b * 256 + gh * 16) * 768;
  for (int idx = tid; idx < 12288; idx += 256) {
    const int gw = idx / 768, col = idx - gw * 768;
    const int ph = col / 48, rem = col - ph * 48;
    const int pw = rem / 3, ii = rem - pw * 3;
    buf[((ph + 1) * 258 + gw * 16 + pw + 1) * 3 + ii] = yb[idx];
  }
  if (gh > 0) {
    const float* yh = y + (b * 256 + (gh - 1) * 16) * 768;
    for (int idx = tid; idx < 768; idx += 256) {
      const int gw = idx / 48, rem = idx - gw * 48;
      const int pw = rem / 3, ii = rem - pw * 3;
      buf[(gw * 16 + pw + 1) * 3 + ii] = yh[gw * 768 + 720 + rem];
    }
  }
  if (gh < 15) {
    const float* yh = y + (b * 256 + (gh + 1) * 16) * 768;
    for (int idx = tid; idx < 768; idx += 256) {
      const int gw = idx / 48, rem = idx - gw * 48;
      const int pw = rem / 3, ii = rem - pw * 3;
      buf[(17 * 258 + gw * 16 + pw + 1) * 3 + ii] = yh[gw * 768 + rem];
    }
  }
  __syncthreads();
  const int c = tid;
  for (int rl = 0; rl < 16; ++rl) {
    float a0 = cbl[0], a1 = cbl[1], a2 = cbl[2];
#pragma unroll
    for (int ky = 0; ky < 3; ++ky)
#pragma unroll
      for (int kx = 0; kx < 3; ++kx)
#pragma unroll
        for (int ii = 0; ii < 3; ++ii) {
          const float v = buf[((rl + ky) * 258 + c + kx) * 3 + ii];
          const int wi = ii * 9 + ky * 3 + kx;
          a0 += v * wl[wi];
          a1 += v * wl[27 + wi];
          a2 += v * wl[54 + wi];
        }
    const long r = gh * 16 + rl;
    out[((b * 3 + 0) * 256 + r) * 256 + c] = a0;
    out[((b * 3 + 1) * 256 + r) * 256 + c] = a1;
    out[((b * 3 + 2) * 256 + r) * 256 + c] = a2;
  }
}

extern "C" void kernel_launch(void* const* d_in, const int* in_sizes, int n_in,
                              void* d_out, int out_size, void* d_ws, size_t ws_size,
                              hipStream_t stream) {
  const float* z_latents = (const float*)d_in[0];
  const float* pos_emb   = (const float*)d_in[1];
  const float* W_embed   = (const float*)d_in[2];
  const float* b_embed   = (const float*)d_in[3];
  const float* ln_pre_w  = (const float*)d_in[4];
  const float* n1_w      = (const float*)d_in[5];
  const float* qkv_w     = (const float*)d_in[6];
  const float* qkv_b     = (const float*)d_in[7];
  const float* proj_w    = (const float*)d_in[8];
  const float* proj_b    = (const float*)d_in[9];
  const float* n2_w      = (const float*)d_in[10];
  const float* w12_w     = (const float*)d_in[11];
  const float* w12_b     = (const float*)d_in[12];
  const float* w3_w      = (const float*)d_in[13];
  const float* w3_b      = (const float*)d_in[14];
  const float* ln_post_w = (const float*)d_in[15];
  const float* conv1_w   = (const float*)d_in[16];
  const float* conv1_b   = (const float*)d_in[17];
  const float* conv_ow   = (const float*)d_in[18];
  const float* conv_ob   = (const float*)d_in[19];
  const float* rope      = (const float*)d_in[20];

  if (ws_size < 598867968ULL) return;
  char* p = (char*)d_ws;
  auto alloc = [&](size_t bytes) { char* r = p; p += (bytes + 255) & ~(size_t)255; return r; };
  float* z    = (float*)alloc(16384L * 768 * 4);
  u16*   h    = (u16*)alloc(16384L * 768 * 2);
  u16*   big  = (u16*)alloc(16384L * 4096 * 2);  // unused (layout stability)
  u16*   q_r  = (u16*)alloc(16384L * 768 * 2);
  u16*   k_s  = (u16*)alloc(16384L * 768 * 2);
  u16*   v_t  = (u16*)alloc(16384L * 768 * 2);
  u16*   ao   = (u16*)alloc(16384L * 768 * 2);
  u16*   u    = (u16*)alloc(16384L * 2048 * 2);
  float* y    = (float*)alloc(16384L * 768 * 4);
  u16* qkvT   = (u16*)alloc(12L * 2304 * 768 * 2);
  u16* projT  = (u16*)alloc(12L * 768 * 768 * 2);
  u16* w12T   = (u16*)alloc(12L * 4096 * 768 * 2);
  u16* w3T    = (u16*)alloc(12L * 768 * 2048 * 2);
  u16* c1T    = (u16*)alloc(768L * 768 * 2);
  (void)big;

  const dim3 tb(32, 8);
  transpose_conv<<<dim3(72, 24, 12), tb, 0, stream>>>(qkv_w, qkvT, 768, 2304, 0);
  transpose_conv<<<dim3(24, 24, 12), tb, 0, stream>>>(proj_w, projT, 768, 768, 0);
  transpose_conv<<<dim3(128, 24, 12), tb, 0, stream>>>(w12_w, w12T, 768, 4096, 2);  // 32-granular x1/x2
  transpose_conv<<<dim3(24, 64, 12), tb, 0, stream>>>(w3_w, w3T, 2048, 768, 0);
  transpose_conv<<<dim3(24, 24, 1), tb, 0, stream>>>(conv1_w, c1T, 768, 768, 0);

  embed_kernel<<<16384, 256, 0, stream>>>(z_latents, pos_emb, W_embed, b_embed, ln_pre_w, z);

  for (int l = 0; l < 12; ++l) {
    rms_wave<<<512, 256, 0, stream>>>(z, n1_w + l * 768, h);
    gemm256<4><<<576, 512, 0, stream>>>(h, qkvT + (long)l * 2304 * 768, nullptr,
                                        qkv_b + l * 2304, 2304, 768, 9,
                                        rope, q_r, k_s, v_t);
    attn_kernel<<<768, 256, 0, stream>>>(q_r, k_s, v_t, ao);
    gemm128s<2><<<768, 256, 0, stream>>>(ao, projT + (long)l * 768 * 768, z,
                                         proj_b + l * 768, 16384, 768, 768, 6, 0,
                                         nullptr, nullptr, nullptr, nullptr);
    rms_wave<<<512, 256, 0, stream>>>(z, n2_w + l * 768, h);
    gemm256<3><<<1024, 512, 0, stream>>>(h, w12T + (long)l * 4096 * 768, u,
                                         w12_b + l * 4096, 4096, 768, 16,
                                         nullptr, nullptr, nullptr, nullptr);
    gemm128s<2><<<768, 256, 0, stream>>>(u, w3T + (long)l * 768 * 2048, z,
                                         w3_b + l * 768, 16384, 768, 2048, 6, 0,
                                         nullptr, nullptr, nullptr, nullptr);
  }

  rms_wave<<<512, 256, 0, stream>>>(z, ln_post_w, h);
  gemm128s<0><<<768, 256, 0, stream>>>(h, c1T, y, conv1_b, 16384, 768, 768, 6, 0,
                                       nullptr, nullptr, nullptr, nullptr);
  conv_out_kernel<<<dim3(16, 64), 256, 0, stream>>>(y, conv_ow, conv_ob, (float*)d_out);
}

// Round 6
// 4824.923 us; speedup vs baseline: 1.1052x; 1.1052x over previous
//
#include <hip/hip_runtime.h>
#include <stdint.h>

typedef unsigned short u16;
typedef __attribute__((ext_vector_type(8))) short short8;
typedef __attribute__((ext_vector_type(4))) float f32x4;

__device__ __forceinline__ float bf2f(u16 u) {
  union { unsigned int i; float f; } x; x.i = ((unsigned int)u) << 16; return x.f;
}
__device__ __forceinline__ u16 f2bf(float f) {
  union { float f; unsigned int i; } x; x.f = f;
  unsigned int r = x.i + 0x7fffu + ((x.i >> 16) & 1u);
  return (u16)(r >> 16);
}

typedef __attribute__((address_space(1))) const unsigned int as1_uint;
typedef __attribute__((address_space(3))) unsigned int as3_uint;

__device__ __forceinline__ void gload_lds16(const void* g, void* l) {
  __builtin_amdgcn_global_load_lds(
      (const as1_uint*)(unsigned long long)g,
      (as3_uint*)(unsigned int)(unsigned long long)l,
      16, 0, 0);
}

// inline-asm LDS read: opaque to the backend waitcnt pass.
__device__ __forceinline__ short8 dsr128(const void* p) {
  short8 r;
  asm volatile("ds_read_b128 %0, %1"
               : "=v"(r)
               : "v"((unsigned int)(unsigned long long)p));
  return r;
}

#define FENCE() asm volatile("" ::: "memory")
#define BAR() do { FENCE(); __builtin_amdgcn_s_barrier(); FENCE(); } while (0)
#define VMCNT(n) asm volatile("s_waitcnt vmcnt(" #n ")" ::: "memory")
#define LGKM0_SB() do { asm volatile("s_waitcnt lgkmcnt(0)"); __builtin_amdgcn_sched_barrier(0); } while (0)

// ---------------- transpose + fp32->bf16 convert: in (L,K,N) f32 -> out (L,N,K) bf16
// perm=2 (w12): output column 32-chunks interleave x1/x2.
__global__ __launch_bounds__(256) void transpose_conv(const float* __restrict__ in, u16* __restrict__ out,
                                                      int K, int N, int perm) {
  __shared__ float tile[32][33];
  const long l = blockIdx.z;
  int nb = blockIdx.x;
  int nbsrc = nb;
  if (perm == 2) {
    nbsrc = (nb & 1) ? 64 + (nb >> 1) : (nb >> 1);
  }
  const int nbS = nbsrc * 32;
  const int nbD = nb * 32;
  const int kb = blockIdx.y * 32;
  const float* I = in + l * (long)K * N;
  u16* O = out + l * (long)N * K;
  const int tx = threadIdx.x, ty = threadIdx.y; // (32,8)
#pragma unroll
  for (int i = 0; i < 32; i += 8)
    tile[ty + i][tx] = I[(long)(kb + ty + i) * N + nbS + tx];
  __syncthreads();
#pragma unroll
  for (int i = 0; i < 32; i += 8)
    O[(long)(nbD + ty + i) * K + kb + tx] = f2bf(tile[tx][ty + i]);
}

// ---------------- embed: z = rms(z_latents @ We + be + pos, ln_pre_w), fp32 out
__global__ __launch_bounds__(256) void embed_kernel(const float* __restrict__ zl, const float* __restrict__ pos,
                                                    const float* __restrict__ We, const float* __restrict__ be,
                                                    const float* __restrict__ lnw, float* __restrict__ z) {
  const long row = blockIdx.x;          // b*256+n
  const int n = (int)(row & 255);
  const int t = threadIdx.x;
  __shared__ float zc[16];
  __shared__ float wsum[4];
  if (t < 16) zc[t] = zl[row * 16 + t];
  __syncthreads();
  float v[3];
#pragma unroll
  for (int e = 0; e < 3; ++e) {
    const int col = t + e * 256;
    float s = be[col] + pos[(long)n * 768 + col];
#pragma unroll
    for (int c = 0; c < 16; ++c) s += zc[c] * We[c * 768 + col];
    v[e] = s;
  }
  float ss = v[0] * v[0] + v[1] * v[1] + v[2] * v[2];
#pragma unroll
  for (int off = 32; off > 0; off >>= 1) ss += __shfl_down(ss, off, 64);
  if ((t & 63) == 0) wsum[t >> 6] = ss;
  __syncthreads();
  const float tot = wsum[0] + wsum[1] + wsum[2] + wsum[3];
  const float rs = rsqrtf(tot * (1.f / 768.f) + 1e-6f);
#pragma unroll
  for (int e = 0; e < 3; ++e) {
    const int col = t + e * 256;
    z[row * 768 + col] = v[e] * rs * lnw[col];
  }
}

// ---------------- wave-parallel rms: 4 waves/block, 8 rows/wave, float4 loads.
__global__ __launch_bounds__(256) void rms_wave(const float* __restrict__ z, const float* __restrict__ w,
                                                u16* __restrict__ h) {
  const int lane = threadIdx.x & 63;
  const int wv = threadIdx.x >> 6;
  float4 wl[3];
#pragma unroll
  for (int k = 0; k < 3; ++k) wl[k] = *(const float4*)(w + k * 256 + lane * 4);
  const long base = ((long)blockIdx.x * 4 + wv) * 8;
  for (int r = 0; r < 8; ++r) {
    const long row = base + r;
    const float* zr = z + row * 768;
    float4 xv[3];
    float ss = 0.f;
#pragma unroll
    for (int k = 0; k < 3; ++k) {
      xv[k] = *(const float4*)(zr + k * 256 + lane * 4);
      ss += xv[k].x * xv[k].x + xv[k].y * xv[k].y + xv[k].z * xv[k].z + xv[k].w * xv[k].w;
    }
#pragma unroll
    for (int o = 1; o < 64; o <<= 1) ss += __shfl_xor(ss, o);
    const float rs = rsqrtf(ss * (1.f / 768.f) + 1e-6f);
    u16* hr = h + row * 768;
#pragma unroll
    for (int k = 0; k < 3; ++k) {
      uint2 pk;
      pk.x = (unsigned int)f2bf(xv[k].x * rs * wl[k].x) | ((unsigned int)f2bf(xv[k].y * rs * wl[k].y) << 16);
      pk.y = (unsigned int)f2bf(xv[k].z * rs * wl[k].z) | ((unsigned int)f2bf(xv[k].w * rs * wl[k].w) << 16);
      *(uint2*)(hr + k * 256 + lane * 4) = pk;
    }
  }
}

// ---------------- 128x128 GEMM, SINGLE-buffered, 48KB LDS pad -> 3 blocks/CU (proven optimum;
// 4 blocks/CU thrashes L2). Per tile:
// {asm ds_read frags; lgkm0; BAR; stage t+1 (DMA overlaps MFMA); MFMA; VMCNT(0); BAR}.
// super (supertile shape, chunk maps to ONE XCD under the wg&7 swizzle; keep WS <= 4MB/XCD):
//   0  = bm-major
//   6  = 8bm x 6bn  (chunk 48 blocks)
//   8  = 8bm x 8bn  (chunk 64 blocks, WS 3.2MB)
//   9  = 4bm x 9bn  (chunk 36 blocks, WS 2.6MB; qkv: A re-read x3 -> x2)
//   16 = 4bm x 16bn (chunk 64 blocks, WS 3.9MB; w12: A re-read x4 -> x2)
// OUT_MODE: 0 = f32 store, 2 = f32 residual +=, 3 = register-fused swiglu (32-granular perm'd w12),
//           4 = fused qkv-bias+RoPE+head-split.
template <int OUT_MODE>
__global__ __launch_bounds__(256, 3) void gemm128s(const u16* __restrict__ A, const u16* __restrict__ Bt,
                                                   void* __restrict__ C, const float* __restrict__ bias,
                                                   int M, int N, int K, int nbn, int super,
                                                   const float* __restrict__ rope, u16* __restrict__ q_r,
                                                   u16* __restrict__ k_s, u16* __restrict__ v_t) {
  __shared__ __align__(16) char ldsc[49152];  // 32KB used (A@0, B@16384); +16KB pad -> 3 blocks/CU
  const int tid = threadIdx.x;
  const int lane = tid & 63;
  const int wave = tid >> 6;
  const int i = lane & 15, g = lane >> 4;
  const int wr = wave >> 1, wc = wave & 1;
  const int xsw = (i & 7) << 4;

  const int wg = blockIdx.x, nwg = gridDim.x;
  const int w2 = (wg & 7) * (nwg >> 3) + (wg >> 3);
  int bm, bn;
  if (super == 16) {       // 4x16 supertile (w12: nbn=32)
    const int s = w2 >> 6, t = w2 & 63;
    const int scols = nbn >> 4;
    bm = ((s / scols) << 2) + (t >> 4);
    bn = ((s % scols) << 4) + (t & 15);
  } else if (super == 9) { // 4x9 supertile (qkv: nbn=18)
    const int s = w2 / 36, t = w2 - s * 36;
    const int scols = nbn / 9;
    bm = ((s / scols) << 2) + t / 9;
    bn = (s % scols) * 9 + t % 9;
  } else if (super == 8) { // 8x8 supertile
    const int s = w2 >> 6, t = w2 & 63;
    const int scols = nbn >> 3;
    bm = ((s / scols) << 3) + (t >> 3);
    bn = ((s % scols) << 3) + (t & 7);
  } else if (super == 6) { // 8x6 supertile
    const int s = w2 / 48, t = w2 % 48;
    const int scols = nbn / 6;
    bm = ((s / scols) << 3) + t / 6;
    bn = (s % scols) * 6 + t % 6;
  } else {
    bm = w2 / nbn; bn = w2 - bm * nbn;
  }
  const long m0 = (long)bm * 128, n0 = (long)bn * 128;

  const u16* Ab_ = A + m0 * K;
  const u16* Bb_ = Bt + n0 * K;
  const int srow = tid >> 3;
  const int scol = ((((tid & 7) * 16) ^ ((srow & 7) << 4)) >> 1);
  const int NT = K >> 6;

  auto stageA = [&](int kk) {
    const u16* s_ = Ab_ + (long)srow * K + kk + scol;
    char* d = ldsc + wave * 1024;
    gload_lds16(s_, d);
    gload_lds16(s_ + 32L * K, d + 4096);
    gload_lds16(s_ + 64L * K, d + 8192);
    gload_lds16(s_ + 96L * K, d + 12288);
  };
  auto stageB = [&](int kk) {
    const u16* s_ = Bb_ + (long)srow * K + kk + scol;
    char* d = ldsc + 16384 + wave * 1024;
    gload_lds16(s_, d);
    gload_lds16(s_ + 32L * K, d + 4096);
    gload_lds16(s_ + 64L * K, d + 8192);
    gload_lds16(s_ + 96L * K, d + 12288);
  };

  f32x4 acc[4][4];
#pragma unroll
  for (int mf = 0; mf < 4; ++mf)
#pragma unroll
    for (int nf = 0; nf < 4; ++nf) { f32x4 zz = {0.f, 0.f, 0.f, 0.f}; acc[mf][nf] = zz; }
  short8 af[4][2], bf[4][2];
  const char* Abuf = ldsc;
  const char* Bbuf = ldsc + 16384;

#define LOAD_A()                                                                                 \
  _Pragma("unroll") for (int r = 0; r < 4; ++r) _Pragma("unroll") for (int s2 = 0; s2 < 2; ++s2) \
      af[r][s2] = dsr128(Abuf + (wr * 64 + r * 16 + i) * 128 + ((s2 * 64 + g * 16) ^ xsw));
#define LOAD_B()                                                                                 \
  _Pragma("unroll") for (int q = 0; q < 4; ++q) _Pragma("unroll") for (int s2 = 0; s2 < 2; ++s2) \
      bf[q][s2] = dsr128(Bbuf + (wc * 64 + q * 16 + i) * 128 + ((s2 * 64 + g * 16) ^ xsw));
#define MFMA_ALL()                                                                               \
  do {                                                                                           \
    __builtin_amdgcn_s_setprio(1);                                                               \
    _Pragma("unroll") for (int r = 0; r < 4; ++r)                                                \
    _Pragma("unroll") for (int q = 0; q < 4; ++q)                                                \
    _Pragma("unroll") for (int s2 = 0; s2 < 2; ++s2)                                             \
        acc[r][q] = __builtin_amdgcn_mfma_f32_16x16x32_bf16(af[r][s2], bf[q][s2], acc[r][q],     \
                                                            0, 0, 0);                            \
    __builtin_amdgcn_s_setprio(0);                                                               \
  } while (0)

  stageA(0); stageB(0);
  VMCNT(0);
  BAR();

  for (int t2 = 0; t2 < NT; ++t2) {
    const bool pf = (t2 + 1 < NT);
    const int k1 = (t2 + 1) * 64;
    LOAD_A(); LOAD_B();
    LGKM0_SB();
    BAR();                                   // all waves finished reading the buffer
    if (pf) { stageA(k1); stageB(k1); }      // overwrite; DMA overlaps MFMA below
    MFMA_ALL();
    if (pf) VMCNT(0);
    BAR();
  }
#undef LOAD_A
#undef LOAD_B
#undef MFMA_ALL

  if constexpr (OUT_MODE == 3) {
    // register-fused swiglu (32-granular perm): wave's fragments nf=0,1 are x1,
    // nf=2,3 are x2 for the SAME output cols. orig col = bn*64 + wc*32 + nf2*16 + i.
    u16* U = (u16*)C;
#pragma unroll
    for (int mf = 0; mf < 4; ++mf) {
      const long rowb = m0 + wr * 64 + mf * 16 + g * 4;
#pragma unroll
      for (int nf2 = 0; nf2 < 2; ++nf2) {
        const int col = bn * 64 + wc * 32 + nf2 * 16 + i;
        const float bv1 = bias[col];
        const float bv2 = bias[2048 + col];
#pragma unroll
        for (int j = 0; j < 4; ++j) {
          const float x1 = acc[mf][nf2][j] + bv1;
          const float x2 = acc[mf][nf2 + 2][j] + bv2;
          const float uu = x1 / (1.f + __expf(-x1)) * x2;
          U[(rowb + j) * 2048 + col] = f2bf(uu);
        }
      }
    }
    return;
  }

  if constexpr (OUT_MODE == 4) {
    // fused qkv epilogue. Block col panel (128) lies in one of q/k/v (768=6*128).
    const int sec = (int)(n0 / 768);              // 0=q 1=k 2=v
    const int head = ((int)(n0 % 768) >> 6) + wc; // wave-uniform
    if (sec == 2) {
#pragma unroll
      for (int mf = 0; mf < 4; ++mf) {
        const long rowb = m0 + wr * 64 + mf * 16 + g * 4;
        const int n = (int)(rowb & 255);
        const long b = rowb >> 8;
        const long bh = b * 12 + head;
        char* vp = (char*)v_t + bh * 32768;
#pragma unroll
        for (int nf = 0; nf < 4; ++nf) {
          const int d = nf * 16 + i;
          const float bv = bias[n0 + wc * 64 + d];
          uint2 pk;
          pk.x = (unsigned int)f2bf(acc[mf][nf][0] + bv) | ((unsigned int)f2bf(acc[mf][nf][1] + bv) << 16);
          pk.y = (unsigned int)f2bf(acc[mf][nf][2] + bv) | ((unsigned int)f2bf(acc[mf][nf][3] + bv) << 16);
          *(uint2*)(vp + d * 512 + ((2 * n) ^ ((d & 7) << 4))) = pk;
        }
      }
    } else {
#pragma unroll
      for (int mf = 0; mf < 4; ++mf) {
        const long rowb = m0 + wr * 64 + mf * 16 + g * 4;
#pragma unroll
        for (int nf = 0; nf < 4; ++nf) {
          const int d = nf * 16 + i;
          const float bv = bias[n0 + wc * 64 + d];
#pragma unroll
          for (int j = 0; j < 4; ++j) {
            const long row = rowb + j;
            const int n = (int)(row & 255);
            const long b = row >> 8;
            const long bh = b * 12 + head;
            const float x = acc[mf][nf][j] + bv;
            const float px = __shfl_xor(x, 1);
            const float cs = rope[n * 128 + d];
            const float sn = rope[n * 128 + 64 + d];
            const float outv = (d & 1) ? x * cs + px * sn : x * cs - px * sn;
            if (sec == 0) {
              q_r[bh * 16384 + (long)n * 64 + d] = f2bf(outv);
            } else {
              char* kp = (char*)k_s + bh * 32768;
              *(u16*)(kp + n * 128 + ((2 * d) ^ ((n & 7) << 4))) = f2bf(outv);
            }
          }
        }
      }
    }
    return;
  }

#pragma unroll
  for (int mf = 0; mf < 4; ++mf) {
    const long row = m0 + wr * 64 + mf * 16 + g * 4;
#pragma unroll
    for (int nf = 0; nf < 4; ++nf) {
      const long col = n0 + wc * 64 + nf * 16 + i;
      const float bv = bias ? bias[col] : 0.f;
#pragma unroll
      for (int j = 0; j < 4; ++j) {
        const float v = acc[mf][nf][j] + bv;
        if constexpr (OUT_MODE == 0) ((float*)C)[(row + j) * N + col] = v;
        else ((float*)C)[(row + j) * N + col] += v;
      }
    }
  }
}

// ---------------- MFMA attention: block = (b,h); 4 waves x 64 query rows; N=256, D=64.
__global__ __launch_bounds__(256) void attn_kernel(const u16* __restrict__ q_r, const u16* __restrict__ k_s,
                                                   const u16* __restrict__ v_t, u16* __restrict__ out) {
  __shared__ __align__(16) u16 Kl[16384];
  __shared__ __align__(16) u16 VTl[16384];
  __shared__ __align__(16) u16 Pl[8192];
  const int tid = threadIdx.x;
  const int lane = tid & 63;
  const int w = tid >> 6;
  const int i = lane & 15;
  const int g = lane >> 4;
  const long bh = blockIdx.x;
  const u16* kg = k_s + bh * 16384;
  const u16* vg = v_t + bh * 16384;
#pragma unroll
  for (int p = 0; p < 8; ++p) {
    gload_lds16(kg + p * 2048 + tid * 8, &Kl[p * 2048 + w * 512]);
    gload_lds16(vg + p * 2048 + tid * 8, &VTl[p * 2048 + w * 512]);
  }
  __syncthreads();

  short8 qv[4][2];
  const u16* qbase = q_r + bh * 16384;
#pragma unroll
  for (int qf = 0; qf < 4; ++qf) {
#pragma unroll
    for (int kc = 0; kc < 2; ++kc)
      qv[qf][kc] = *(const short8*)(qbase + (w * 64 + qf * 16 + i) * 64 + kc * 32 + g * 8);
  }

  f32x4 o[4][4];
#pragma unroll
  for (int df = 0; df < 4; ++df)
#pragma unroll
    for (int qf = 0; qf < 4; ++qf) { f32x4 zz = {0.f, 0.f, 0.f, 0.f}; o[df][qf] = zz; }
  float m[4], l[4];
#pragma unroll
  for (int qf = 0; qf < 4; ++qf) { m[qf] = -1e30f; l[qf] = 0.f; }

  char* pw = (char*)Pl + w * 4096;

  for (int c = 0; c < 8; ++c) {
    f32x4 st[2][4];
#pragma unroll
    for (int f = 0; f < 2; ++f)
#pragma unroll
      for (int qf = 0; qf < 4; ++qf) { f32x4 zz = {0.f, 0.f, 0.f, 0.f}; st[f][qf] = zz; }
    __builtin_amdgcn_s_setprio(1);
#pragma unroll
    for (int f = 0; f < 2; ++f) {
      const int kv = c * 32 + f * 16 + i;
#pragma unroll
      for (int kc = 0; kc < 2; ++kc) {
        short8 kf = *(const short8*)((const char*)Kl + kv * 128 + (((kc * 64 + g * 16)) ^ ((kv & 7) << 4)));
#pragma unroll
        for (int qf = 0; qf < 4; ++qf)
          st[f][qf] = __builtin_amdgcn_mfma_f32_16x16x32_bf16(kf, qv[qf][kc], st[f][qf], 0, 0, 0);
      }
    }
    __builtin_amdgcn_s_setprio(0);
#pragma unroll
    for (int qf = 0; qf < 4; ++qf) {
      float s[8];
#pragma unroll
      for (int f = 0; f < 2; ++f)
#pragma unroll
        for (int j = 0; j < 4; ++j) s[f * 4 + j] = st[f][qf][j] * 0.125f;
      float cm = fmaxf(fmaxf(fmaxf(s[0], s[1]), fmaxf(s[2], s[3])),
                       fmaxf(fmaxf(s[4], s[5]), fmaxf(s[6], s[7])));
      cm = fmaxf(cm, __shfl_xor(cm, 16));
      cm = fmaxf(cm, __shfl_xor(cm, 32));
      const bool upd = cm > m[qf] + 8.f;  // defer-max (T13)
      const float newm = upd ? cm : m[qf];
      const float fac = __expf(m[qf] - newm);
      float psum = 0.f;
      u16 pb[8];
#pragma unroll
      for (int t2 = 0; t2 < 8; ++t2) {
        const float p = __expf(s[t2] - newm);
        psum += p;
        pb[t2] = f2bf(p);
      }
      l[qf] = l[qf] * fac + psum;
      m[qf] = newm;
      if (__any(upd)) {
#pragma unroll
        for (int df = 0; df < 4; ++df)
#pragma unroll
          for (int j = 0; j < 4; ++j) o[df][qf][j] *= fac;
      }
      char* pbase = pw + (qf * 16 + i) * 64 + g * 8;
      uint2 w0, w1;
      w0.x = (unsigned int)pb[0] | ((unsigned int)pb[1] << 16);
      w0.y = (unsigned int)pb[2] | ((unsigned int)pb[3] << 16);
      w1.x = (unsigned int)pb[4] | ((unsigned int)pb[5] << 16);
      w1.y = (unsigned int)pb[6] | ((unsigned int)pb[7] << 16);
      *(uint2*)(pbase) = w0;
      *(uint2*)(pbase + 32) = w1;
    }
    short8 pf[4];
#pragma unroll
    for (int qf = 0; qf < 4; ++qf)
      pf[qf] = *(const short8*)(pw + (qf * 16 + i) * 64 + g * 16);
    __builtin_amdgcn_s_setprio(1);
#pragma unroll
    for (int df = 0; df < 4; ++df) {
      const int d = df * 16 + i;
      short8 vf = *(const short8*)((const char*)VTl + d * 512 + ((c * 64 + g * 16) ^ ((d & 7) << 4)));
#pragma unroll
      for (int qf = 0; qf < 4; ++qf)
        o[df][qf] = __builtin_amdgcn_mfma_f32_16x16x32_bf16(vf, pf[qf], o[df][qf], 0, 0, 0);
    }
    __builtin_amdgcn_s_setprio(0);
  }

#pragma unroll
  for (int qf = 0; qf < 4; ++qf) {
    l[qf] += __shfl_xor(l[qf], 16);
    l[qf] += __shfl_xor(l[qf], 32);
  }

  const long b = bh / 12;
  const int hh = (int)(bh % 12);
#pragma unroll
  for (int qf = 0; qf < 4; ++qf) {
    const float inv = 1.f / l[qf];
    const long q = w * 64 + qf * 16 + i;
    u16* op = out + (b * 256 + q) * 768 + hh * 64;
#pragma unroll
    for (int df = 0; df < 4; ++df) {
      const int d0 = df * 16 + g * 4;
      unsigned int a = (unsigned int)f2bf(o[df][qf][0] * inv) | ((unsigned int)f2bf(o[df][qf][1] * inv) << 16);
      unsigned int bb = (unsigned int)f2bf(o[df][qf][2] * inv) | ((unsigned int)f2bf(o[df][qf][3] * inv) << 16);
      *(unsigned int*)(op + d0) = a;
      *(unsigned int*)(op + d0 + 2) = bb;
    }
  }
}

// ---------------- pixel shuffle + 3x3 SAME conv + bias, LDS-tiled.
__global__ __launch_bounds__(256) void conv_out_kernel(const float* __restrict__ y, const float* __restrict__ w,
                                                       const float* __restrict__ cb, float* __restrict__ out) {
  __shared__ float buf[18 * 258 * 3];
  __shared__ float wl[81];
  __shared__ float cbl[3];
  const int tid = threadIdx.x;
  const int gh = blockIdx.x;
  const long b = blockIdx.y;
  for (int idx = tid; idx < 18 * 258 * 3; idx += 256) buf[idx] = 0.f;
  if (tid < 81) wl[tid] = w[tid];
  if (tid < 3) cbl[tid] = cb[tid];
  __syncthreads();
  const float* yb = y + (b * 256 + gh * 16) * 768;
  for (int idx = tid; idx < 12288; idx += 256) {
    const int gw = idx / 768, col = idx - gw * 768;
    const int ph = col / 48, rem = col - ph * 48;
    const int pw = rem / 3, ii = rem - pw * 3;
    buf[((ph + 1) * 258 + gw * 16 + pw + 1) * 3 + ii] = yb[idx];
  }
  if (gh > 0) {
    const float* yh = y + (b * 256 + (gh - 1) * 16) * 768;
    for (int idx = tid; idx < 768; idx += 256) {
      const int gw = idx / 48, rem = idx - gw * 48;
      const int pw = rem / 3, ii = rem - pw * 3;
      buf[(gw * 16 + pw + 1) * 3 + ii] = yh[gw * 768 + 720 + rem];
    }
  }
  if (gh < 15) {
    const float* yh = y + (b * 256 + (gh + 1) * 16) * 768;
    for (int idx = tid; idx < 768; idx += 256) {
      const int gw = idx / 48, rem = idx - gw * 48;
      const int pw = rem / 3, ii = rem - pw * 3;
      buf[(17 * 258 + gw * 16 + pw + 1) * 3 + ii] = yh[gw * 768 + rem];
    }
  }
  __syncthreads();
  const int c = tid;
  for (int rl = 0; rl < 16; ++rl) {
    float a0 = cbl[0], a1 = cbl[1], a2 = cbl[2];
#pragma unroll
    for (int ky = 0; ky < 3; ++ky)
#pragma unroll
      for (int kx = 0; kx < 3; ++kx)
#pragma unroll
        for (int ii = 0; ii < 3; ++ii) {
          const float v = buf[((rl + ky) * 258 + c + kx) * 3 + ii];
          const int wi = ii * 9 + ky * 3 + kx;
          a0 += v * wl[wi];
          a1 += v * wl[27 + wi];
          a2 += v * wl[54 + wi];
        }
    const long r = gh * 16 + rl;
    out[((b * 3 + 0) * 256 + r) * 256 + c] = a0;
    out[((b * 3 + 1) * 256 + r) * 256 + c] = a1;
    out[((b * 3 + 2) * 256 + r) * 256 + c] = a2;
  }
}

extern "C" void kernel_launch(void* const* d_in, const int* in_sizes, int n_in,
                              void* d_out, int out_size, void* d_ws, size_t ws_size,
                              hipStream_t stream) {
  const float* z_latents = (const float*)d_in[0];
  const float* pos_emb   = (const float*)d_in[1];
  const float* W_embed   = (const float*)d_in[2];
  const float* b_embed   = (const float*)d_in[3];
  const float* ln_pre_w  = (const float*)d_in[4];
  const float* n1_w      = (const float*)d_in[5];
  const float* qkv_w     = (const float*)d_in[6];
  const float* qkv_b     = (const float*)d_in[7];
  const float* proj_w    = (const float*)d_in[8];
  const float* proj_b    = (const float*)d_in[9];
  const float* n2_w      = (const float*)d_in[10];
  const float* w12_w     = (const float*)d_in[11];
  const float* w12_b     = (const float*)d_in[12];
  const float* w3_w      = (const float*)d_in[13];
  const float* w3_b      = (const float*)d_in[14];
  const float* ln_post_w = (const float*)d_in[15];
  const float* conv1_w   = (const float*)d_in[16];
  const float* conv1_b   = (const float*)d_in[17];
  const float* conv_ow   = (const float*)d_in[18];
  const float* conv_ob   = (const float*)d_in[19];
  const float* rope      = (const float*)d_in[20];

  if (ws_size < 598867968ULL) return;
  char* p = (char*)d_ws;
  auto alloc = [&](size_t bytes) { char* r = p; p += (bytes + 255) & ~(size_t)255; return r; };
  float* z    = (float*)alloc(16384L * 768 * 4);
  u16*   h    = (u16*)alloc(16384L * 768 * 2);
  u16*   big  = (u16*)alloc(16384L * 4096 * 2);  // unused (layout stability)
  u16*   q_r  = (u16*)alloc(16384L * 768 * 2);
  u16*   k_s  = (u16*)alloc(16384L * 768 * 2);
  u16*   v_t  = (u16*)alloc(16384L * 768 * 2);
  u16*   ao   = (u16*)alloc(16384L * 768 * 2);
  u16*   u    = (u16*)alloc(16384L * 2048 * 2);
  float* y    = (float*)alloc(16384L * 768 * 4);
  u16* qkvT   = (u16*)alloc(12L * 2304 * 768 * 2);
  u16* projT  = (u16*)alloc(12L * 768 * 768 * 2);
  u16* w12T   = (u16*)alloc(12L * 4096 * 768 * 2);
  u16* w3T    = (u16*)alloc(12L * 768 * 2048 * 2);
  u16* c1T    = (u16*)alloc(768L * 768 * 2);
  (void)big;

  const dim3 tb(32, 8);
  transpose_conv<<<dim3(72, 24, 12), tb, 0, stream>>>(qkv_w, qkvT, 768, 2304, 0);
  transpose_conv<<<dim3(24, 24, 12), tb, 0, stream>>>(proj_w, projT, 768, 768, 0);
  transpose_conv<<<dim3(128, 24, 12), tb, 0, stream>>>(w12_w, w12T, 768, 4096, 2);  // 32-granular x1/x2
  transpose_conv<<<dim3(24, 64, 12), tb, 0, stream>>>(w3_w, w3T, 2048, 768, 0);
  transpose_conv<<<dim3(24, 24, 1), tb, 0, stream>>>(conv1_w, c1T, 768, 768, 0);

  embed_kernel<<<16384, 256, 0, stream>>>(z_latents, pos_emb, W_embed, b_embed, ln_pre_w, z);

  for (int l = 0; l < 12; ++l) {
    rms_wave<<<512, 256, 0, stream>>>(z, n1_w + l * 768, h);
    gemm128s<4><<<2304, 256, 0, stream>>>(h, qkvT + (long)l * 2304 * 768, nullptr,
                                          qkv_b + l * 2304, 16384, 2304, 768, 18, 9,
                                          rope, q_r, k_s, v_t);
    attn_kernel<<<768, 256, 0, stream>>>(q_r, k_s, v_t, ao);
    gemm128s<2><<<768, 256, 0, stream>>>(ao, projT + (long)l * 768 * 768, z,
                                         proj_b + l * 768, 16384, 768, 768, 6, 0,
                                         nullptr, nullptr, nullptr, nullptr);
    rms_wave<<<512, 256, 0, stream>>>(z, n2_w + l * 768, h);
    gemm128s<3><<<4096, 256, 0, stream>>>(h, w12T + (long)l * 4096 * 768, u,
                                          w12_b + l * 4096, 16384, 4096, 768, 32, 16,
                                          nullptr, nullptr, nullptr, nullptr);
    gemm128s<2><<<768, 256, 0, stream>>>(u, w3T + (long)l * 768 * 2048, z,
                                         w3_b + l * 768, 16384, 768, 2048, 6, 0,
                                         nullptr, nullptr, nullptr, nullptr);
  }

  rms_wave<<<512, 256, 0, stream>>>(z, ln_post_w, h);
  gemm128s<0><<<768, 256, 0, stream>>>(h, c1T, y, conv1_b, 16384, 768, 768, 6, 0,
                                       nullptr, nullptr, nullptr, nullptr);
  conv_out_kernel<<<dim3(16, 64), 256, 0, stream>>>(y, conv_ow, conv_ob, (float*)d_out);
}

// Round 7
// 4746.675 us; speedup vs baseline: 1.1234x; 1.0165x over previous
//
#include <hip/hip_runtime.h>
#include <stdint.h>

typedef unsigned short u16;
typedef __attribute__((ext_vector_type(8))) short short8;
typedef __attribute__((ext_vector_type(4))) float f32x4;

__device__ __forceinline__ float bf2f(u16 u) {
  union { unsigned int i; float f; } x; x.i = ((unsigned int)u) << 16; return x.f;
}
__device__ __forceinline__ u16 f2bf(float f) {
  union { float f; unsigned int i; } x; x.f = f;
  unsigned int r = x.i + 0x7fffu + ((x.i >> 16) & 1u);
  return (u16)(r >> 16);
}

typedef __attribute__((address_space(1))) const unsigned int as1_uint;
typedef __attribute__((address_space(3))) unsigned int as3_uint;

__device__ __forceinline__ void gload_lds16(const void* g, void* l) {
  __builtin_amdgcn_global_load_lds(
      (const as1_uint*)(unsigned long long)g,
      (as3_uint*)(unsigned int)(unsigned long long)l,
      16, 0, 0);
}

// inline-asm LDS read: opaque to the backend waitcnt pass.
__device__ __forceinline__ short8 dsr128(const void* p) {
  short8 r;
  asm volatile("ds_read_b128 %0, %1"
               : "=v"(r)
               : "v"((unsigned int)(unsigned long long)p));
  return r;
}

#define FENCE() asm volatile("" ::: "memory")
#define BAR() do { FENCE(); __builtin_amdgcn_s_barrier(); FENCE(); } while (0)
#define VMCNT(n) asm volatile("s_waitcnt vmcnt(" #n ")" ::: "memory")
#define LGKM0_SB() do { asm volatile("s_waitcnt lgkmcnt(0)"); __builtin_amdgcn_sched_barrier(0); } while (0)

// ---------------- transpose + fp32->bf16 convert: in (L,K,N) f32 -> out (L,N,K) bf16
// perm=2 (w12): output column 32-chunks interleave x1/x2.
__global__ __launch_bounds__(256) void transpose_conv(const float* __restrict__ in, u16* __restrict__ out,
                                                      int K, int N, int perm) {
  __shared__ float tile[32][33];
  const long l = blockIdx.z;
  int nb = blockIdx.x;
  int nbsrc = nb;
  if (perm == 2) {
    nbsrc = (nb & 1) ? 64 + (nb >> 1) : (nb >> 1);
  }
  const int nbS = nbsrc * 32;
  const int nbD = nb * 32;
  const int kb = blockIdx.y * 32;
  const float* I = in + l * (long)K * N;
  u16* O = out + l * (long)N * K;
  const int tx = threadIdx.x, ty = threadIdx.y; // (32,8)
#pragma unroll
  for (int i = 0; i < 32; i += 8)
    tile[ty + i][tx] = I[(long)(kb + ty + i) * N + nbS + tx];
  __syncthreads();
#pragma unroll
  for (int i = 0; i < 32; i += 8)
    O[(long)(nbD + ty + i) * K + kb + tx] = f2bf(tile[tx][ty + i]);
}

// ---------------- embed: z = rms(z_latents @ We + be + pos, ln_pre_w), fp32 out
__global__ __launch_bounds__(256) void embed_kernel(const float* __restrict__ zl, const float* __restrict__ pos,
                                                    const float* __restrict__ We, const float* __restrict__ be,
                                                    const float* __restrict__ lnw, float* __restrict__ z) {
  const long row = blockIdx.x;          // b*256+n
  const int n = (int)(row & 255);
  const int t = threadIdx.x;
  __shared__ float zc[16];
  __shared__ float wsum[4];
  if (t < 16) zc[t] = zl[row * 16 + t];
  __syncthreads();
  float v[3];
#pragma unroll
  for (int e = 0; e < 3; ++e) {
    const int col = t + e * 256;
    float s = be[col] + pos[(long)n * 768 + col];
#pragma unroll
    for (int c = 0; c < 16; ++c) s += zc[c] * We[c * 768 + col];
    v[e] = s;
  }
  float ss = v[0] * v[0] + v[1] * v[1] + v[2] * v[2];
#pragma unroll
  for (int off = 32; off > 0; off >>= 1) ss += __shfl_down(ss, off, 64);
  if ((t & 63) == 0) wsum[t >> 6] = ss;
  __syncthreads();
  const float tot = wsum[0] + wsum[1] + wsum[2] + wsum[3];
  const float rs = rsqrtf(tot * (1.f / 768.f) + 1e-6f);
#pragma unroll
  for (int e = 0; e < 3; ++e) {
    const int col = t + e * 256;
    z[row * 768 + col] = v[e] * rs * lnw[col];
  }
}

// ---------------- wave-parallel rms: 4 waves/block, 8 rows/wave, float4 loads.
__global__ __launch_bounds__(256) void rms_wave(const float* __restrict__ z, const float* __restrict__ w,
                                                u16* __restrict__ h) {
  const int lane = threadIdx.x & 63;
  const int wv = threadIdx.x >> 6;
  float4 wl[3];
#pragma unroll
  for (int k = 0; k < 3; ++k) wl[k] = *(const float4*)(w + k * 256 + lane * 4);
  const long base = ((long)blockIdx.x * 4 + wv) * 8;
  for (int r = 0; r < 8; ++r) {
    const long row = base + r;
    const float* zr = z + row * 768;
    float4 xv[3];
    float ss = 0.f;
#pragma unroll
    for (int k = 0; k < 3; ++k) {
      xv[k] = *(const float4*)(zr + k * 256 + lane * 4);
      ss += xv[k].x * xv[k].x + xv[k].y * xv[k].y + xv[k].z * xv[k].z + xv[k].w * xv[k].w;
    }
#pragma unroll
    for (int o = 1; o < 64; o <<= 1) ss += __shfl_xor(ss, o);
    const float rs = rsqrtf(ss * (1.f / 768.f) + 1e-6f);
    u16* hr = h + row * 768;
#pragma unroll
    for (int k = 0; k < 3; ++k) {
      uint2 pk;
      pk.x = (unsigned int)f2bf(xv[k].x * rs * wl[k].x) | ((unsigned int)f2bf(xv[k].y * rs * wl[k].y) << 16);
      pk.y = (unsigned int)f2bf(xv[k].z * rs * wl[k].z) | ((unsigned int)f2bf(xv[k].w * rs * wl[k].w) << 16);
      *(uint2*)(hr + k * 256 + lane * 4) = pk;
    }
  }
}

// ---------------- 128x128 GEMM, SINGLE-buffered, 48KB LDS pad -> 3 blocks/CU (proven optimum;
// 4 blocks/CU thrashes L2). Per tile:
// {asm ds_read frags; lgkm0; BAR; stage t+1 (DMA overlaps MFMA); MFMA; VMCNT(0); BAR}.
// super (supertile shape):
//   0  = bm-major
//   6  = 8bm x 6bn  (qkv: proven; 4x9 regressed 1st dispatch 192us -- round 6)
//   8  = 8bm x 8bn
//   16 = 4bm x 16bn (w12: A-chunk 0.8MB stays L2-hot -> staged-A hits; -4us/dispatch, round 6)
// OUT_MODE: 0 = f32 store, 2 = f32 residual +=, 3 = register-fused swiglu (32-granular perm'd w12),
//           4 = fused qkv-bias+RoPE+head-split.
template <int OUT_MODE>
__global__ __launch_bounds__(256, 3) void gemm128s(const u16* __restrict__ A, const u16* __restrict__ Bt,
                                                   void* __restrict__ C, const float* __restrict__ bias,
                                                   int M, int N, int K, int nbn, int super,
                                                   const float* __restrict__ rope, u16* __restrict__ q_r,
                                                   u16* __restrict__ k_s, u16* __restrict__ v_t) {
  __shared__ __align__(16) char ldsc[49152];  // 32KB used (A@0, B@16384); +16KB pad -> 3 blocks/CU
  const int tid = threadIdx.x;
  const int lane = tid & 63;
  const int wave = tid >> 6;
  const int i = lane & 15, g = lane >> 4;
  const int wr = wave >> 1, wc = wave & 1;
  const int xsw = (i & 7) << 4;

  const int wg = blockIdx.x, nwg = gridDim.x;
  const int w2 = (wg & 7) * (nwg >> 3) + (wg >> 3);
  int bm, bn;
  if (super == 16) {       // 4x16 supertile (w12: nbn=32)
    const int s = w2 >> 6, t = w2 & 63;
    const int scols = nbn >> 4;
    bm = ((s / scols) << 2) + (t >> 4);
    bn = ((s % scols) << 4) + (t & 15);
  } else if (super == 8) { // 8x8 supertile
    const int s = w2 >> 6, t = w2 & 63;
    const int scols = nbn >> 3;
    bm = ((s / scols) << 3) + (t >> 3);
    bn = ((s % scols) << 3) + (t & 7);
  } else if (super == 6) { // 8x6 supertile
    const int s = w2 / 48, t = w2 % 48;
    const int scols = nbn / 6;
    bm = ((s / scols) << 3) + t / 6;
    bn = (s % scols) * 6 + t % 6;
  } else {
    bm = w2 / nbn; bn = w2 - bm * nbn;
  }
  const long m0 = (long)bm * 128, n0 = (long)bn * 128;

  const u16* Ab_ = A + m0 * K;
  const u16* Bb_ = Bt + n0 * K;
  const int srow = tid >> 3;
  const int scol = ((((tid & 7) * 16) ^ ((srow & 7) << 4)) >> 1);
  const int NT = K >> 6;

  auto stageA = [&](int kk) {
    const u16* s_ = Ab_ + (long)srow * K + kk + scol;
    char* d = ldsc + wave * 1024;
    gload_lds16(s_, d);
    gload_lds16(s_ + 32L * K, d + 4096);
    gload_lds16(s_ + 64L * K, d + 8192);
    gload_lds16(s_ + 96L * K, d + 12288);
  };
  auto stageB = [&](int kk) {
    const u16* s_ = Bb_ + (long)srow * K + kk + scol;
    char* d = ldsc + 16384 + wave * 1024;
    gload_lds16(s_, d);
    gload_lds16(s_ + 32L * K, d + 4096);
    gload_lds16(s_ + 64L * K, d + 8192);
    gload_lds16(s_ + 96L * K, d + 12288);
  };

  f32x4 acc[4][4];
#pragma unroll
  for (int mf = 0; mf < 4; ++mf)
#pragma unroll
    for (int nf = 0; nf < 4; ++nf) { f32x4 zz = {0.f, 0.f, 0.f, 0.f}; acc[mf][nf] = zz; }
  short8 af[4][2], bf[4][2];
  const char* Abuf = ldsc;
  const char* Bbuf = ldsc + 16384;

#define LOAD_A()                                                                                 \
  _Pragma("unroll") for (int r = 0; r < 4; ++r) _Pragma("unroll") for (int s2 = 0; s2 < 2; ++s2) \
      af[r][s2] = dsr128(Abuf + (wr * 64 + r * 16 + i) * 128 + ((s2 * 64 + g * 16) ^ xsw));
#define LOAD_B()                                                                                 \
  _Pragma("unroll") for (int q = 0; q < 4; ++q) _Pragma("unroll") for (int s2 = 0; s2 < 2; ++s2) \
      bf[q][s2] = dsr128(Bbuf + (wc * 64 + q * 16 + i) * 128 + ((s2 * 64 + g * 16) ^ xsw));
#define MFMA_ALL()                                                                               \
  do {                                                                                           \
    __builtin_amdgcn_s_setprio(1);                                                               \
    _Pragma("unroll") for (int r = 0; r < 4; ++r)                                                \
    _Pragma("unroll") for (int q = 0; q < 4; ++q)                                                \
    _Pragma("unroll") for (int s2 = 0; s2 < 2; ++s2)                                             \
        acc[r][q] = __builtin_amdgcn_mfma_f32_16x16x32_bf16(af[r][s2], bf[q][s2], acc[r][q],     \
                                                            0, 0, 0);                            \
    __builtin_amdgcn_s_setprio(0);                                                               \
  } while (0)

  stageA(0); stageB(0);
  VMCNT(0);
  BAR();

  for (int t2 = 0; t2 < NT; ++t2) {
    const bool pf = (t2 + 1 < NT);
    const int k1 = (t2 + 1) * 64;
    LOAD_A(); LOAD_B();
    LGKM0_SB();
    BAR();                                   // all waves finished reading the buffer
    if (pf) { stageA(k1); stageB(k1); }      // overwrite; DMA overlaps MFMA below
    MFMA_ALL();
    if (pf) VMCNT(0);
    BAR();
  }
#undef LOAD_A
#undef LOAD_B
#undef MFMA_ALL

  if constexpr (OUT_MODE == 3) {
    // register-fused swiglu (32-granular perm): wave's fragments nf=0,1 are x1,
    // nf=2,3 are x2 for the SAME output cols. orig col = bn*64 + wc*32 + nf2*16 + i.
    u16* U = (u16*)C;
#pragma unroll
    for (int mf = 0; mf < 4; ++mf) {
      const long rowb = m0 + wr * 64 + mf * 16 + g * 4;
#pragma unroll
      for (int nf2 = 0; nf2 < 2; ++nf2) {
        const int col = bn * 64 + wc * 32 + nf2 * 16 + i;
        const float bv1 = bias[col];
        const float bv2 = bias[2048 + col];
#pragma unroll
        for (int j = 0; j < 4; ++j) {
          const float x1 = acc[mf][nf2][j] + bv1;
          const float x2 = acc[mf][nf2 + 2][j] + bv2;
          const float uu = x1 / (1.f + __expf(-x1)) * x2;
          U[(rowb + j) * 2048 + col] = f2bf(uu);
        }
      }
    }
    return;
  }

  if constexpr (OUT_MODE == 4) {
    // fused qkv epilogue. Block col panel (128) lies in one of q/k/v (768=6*128).
    const int sec = (int)(n0 / 768);              // 0=q 1=k 2=v
    const int head = ((int)(n0 % 768) >> 6) + wc; // wave-uniform
    if (sec == 2) {
#pragma unroll
      for (int mf = 0; mf < 4; ++mf) {
        const long rowb = m0 + wr * 64 + mf * 16 + g * 4;
        const int n = (int)(rowb & 255);
        const long b = rowb >> 8;
        const long bh = b * 12 + head;
        char* vp = (char*)v_t + bh * 32768;
#pragma unroll
        for (int nf = 0; nf < 4; ++nf) {
          const int d = nf * 16 + i;
          const float bv = bias[n0 + wc * 64 + d];
          uint2 pk;
          pk.x = (unsigned int)f2bf(acc[mf][nf][0] + bv) | ((unsigned int)f2bf(acc[mf][nf][1] + bv) << 16);
          pk.y = (unsigned int)f2bf(acc[mf][nf][2] + bv) | ((unsigned int)f2bf(acc[mf][nf][3] + bv) << 16);
          *(uint2*)(vp + d * 512 + ((2 * n) ^ ((d & 7) << 4))) = pk;
        }
      }
    } else {
#pragma unroll
      for (int mf = 0; mf < 4; ++mf) {
        const long rowb = m0 + wr * 64 + mf * 16 + g * 4;
#pragma unroll
        for (int nf = 0; nf < 4; ++nf) {
          const int d = nf * 16 + i;
          const float bv = bias[n0 + wc * 64 + d];
#pragma unroll
          for (int j = 0; j < 4; ++j) {
            const long row = rowb + j;
            const int n = (int)(row & 255);
            const long b = row >> 8;
            const long bh = b * 12 + head;
            const float x = acc[mf][nf][j] + bv;
            const float px = __shfl_xor(x, 1);
            const float cs = rope[n * 128 + d];
            const float sn = rope[n * 128 + 64 + d];
            const float outv = (d & 1) ? x * cs + px * sn : x * cs - px * sn;
            if (sec == 0) {
              q_r[bh * 16384 + (long)n * 64 + d] = f2bf(outv);
            } else {
              char* kp = (char*)k_s + bh * 32768;
              *(u16*)(kp + n * 128 + ((2 * d) ^ ((n & 7) << 4))) = f2bf(outv);
            }
          }
        }
      }
    }
    return;
  }

#pragma unroll
  for (int mf = 0; mf < 4; ++mf) {
    const long row = m0 + wr * 64 + mf * 16 + g * 4;
#pragma unroll
    for (int nf = 0; nf < 4; ++nf) {
      const long col = n0 + wc * 64 + nf * 16 + i;
      const float bv = bias ? bias[col] : 0.f;
#pragma unroll
      for (int j = 0; j < 4; ++j) {
        const float v = acc[mf][nf][j] + bv;
        if constexpr (OUT_MODE == 0) ((float*)C)[(row + j) * N + col] = v;
        else ((float*)C)[(row + j) * N + col] += v;
      }
    }
  }
}

// ---------------- MFMA attention: block = (b,h); 4 waves x 64 query rows; N=256, D=64.
// P round-trip through LDS is XOR-swizzled with ((i&12)<<2): without it both the
// uint2 writes and the b128 read hit only 8 distinct banks (8-way conflict, ~2.9x);
// with it <=2-way (free). Write/read use the same key; each offset XOR'd separately
// (base+32 would carry out of the 64B row).
__global__ __launch_bounds__(256) void attn_kernel(const u16* __restrict__ q_r, const u16* __restrict__ k_s,
                                                   const u16* __restrict__ v_t, u16* __restrict__ out) {
  __shared__ __align__(16) u16 Kl[16384];
  __shared__ __align__(16) u16 VTl[16384];
  __shared__ __align__(16) u16 Pl[8192];
  const int tid = threadIdx.x;
  const int lane = tid & 63;
  const int w = tid >> 6;
  const int i = lane & 15;
  const int g = lane >> 4;
  const long bh = blockIdx.x;
  const u16* kg = k_s + bh * 16384;
  const u16* vg = v_t + bh * 16384;
#pragma unroll
  for (int p = 0; p < 8; ++p) {
    gload_lds16(kg + p * 2048 + tid * 8, &Kl[p * 2048 + w * 512]);
    gload_lds16(vg + p * 2048 + tid * 8, &VTl[p * 2048 + w * 512]);
  }
  __syncthreads();

  short8 qv[4][2];
  const u16* qbase = q_r + bh * 16384;
#pragma unroll
  for (int qf = 0; qf < 4; ++qf) {
#pragma unroll
    for (int kc = 0; kc < 2; ++kc)
      qv[qf][kc] = *(const short8*)(qbase + (w * 64 + qf * 16 + i) * 64 + kc * 32 + g * 8);
  }

  f32x4 o[4][4];
#pragma unroll
  for (int df = 0; df < 4; ++df)
#pragma unroll
    for (int qf = 0; qf < 4; ++qf) { f32x4 zz = {0.f, 0.f, 0.f, 0.f}; o[df][qf] = zz; }
  float m[4], l[4];
#pragma unroll
  for (int qf = 0; qf < 4; ++qf) { m[qf] = -1e30f; l[qf] = 0.f; }

  char* pw = (char*)Pl + w * 4096;
  const int X = (i & 12) << 2;  // P-LDS anti-conflict XOR key (16B-multiple)

  for (int c = 0; c < 8; ++c) {
    f32x4 st[2][4];
#pragma unroll
    for (int f = 0; f < 2; ++f)
#pragma unroll
      for (int qf = 0; qf < 4; ++qf) { f32x4 zz = {0.f, 0.f, 0.f, 0.f}; st[f][qf] = zz; }
    __builtin_amdgcn_s_setprio(1);
#pragma unroll
    for (int f = 0; f < 2; ++f) {
      const int kv = c * 32 + f * 16 + i;
#pragma unroll
      for (int kc = 0; kc < 2; ++kc) {
        short8 kf = *(const short8*)((const char*)Kl + kv * 128 + (((kc * 64 + g * 16)) ^ ((kv & 7) << 4)));
#pragma unroll
        for (int qf = 0; qf < 4; ++qf)
          st[f][qf] = __builtin_amdgcn_mfma_f32_16x16x32_bf16(kf, qv[qf][kc], st[f][qf], 0, 0, 0);
      }
    }
    __builtin_amdgcn_s_setprio(0);
#pragma unroll
    for (int qf = 0; qf < 4; ++qf) {
      float s[8];
#pragma unroll
      for (int f = 0; f < 2; ++f)
#pragma unroll
        for (int j = 0; j < 4; ++j) s[f * 4 + j] = st[f][qf][j] * 0.125f;
      float cm = fmaxf(fmaxf(fmaxf(s[0], s[1]), fmaxf(s[2], s[3])),
                       fmaxf(fmaxf(s[4], s[5]), fmaxf(s[6], s[7])));
      cm = fmaxf(cm, __shfl_xor(cm, 16));
      cm = fmaxf(cm, __shfl_xor(cm, 32));
      const bool upd = cm > m[qf] + 8.f;  // defer-max (T13)
      const float newm = upd ? cm : m[qf];
      const float fac = __expf(m[qf] - newm);
      float psum = 0.f;
      u16 pb[8];
#pragma unroll
      for (int t2 = 0; t2 < 8; ++t2) {
        const float p = __expf(s[t2] - newm);
        psum += p;
        pb[t2] = f2bf(p);
      }
      l[qf] = l[qf] * fac + psum;
      m[qf] = newm;
      if (__any(upd)) {
#pragma unroll
        for (int df = 0; df < 4; ++df)
#pragma unroll
          for (int j = 0; j < 4; ++j) o[df][qf][j] *= fac;
      }
      char* prow = pw + (qf * 16 + i) * 64;
      uint2 w0, w1;
      w0.x = (unsigned int)pb[0] | ((unsigned int)pb[1] << 16);
      w0.y = (unsigned int)pb[2] | ((unsigned int)pb[3] << 16);
      w1.x = (unsigned int)pb[4] | ((unsigned int)pb[5] << 16);
      w1.y = (unsigned int)pb[6] | ((unsigned int)pb[7] << 16);
      *(uint2*)(prow + ((g * 8) ^ X)) = w0;
      *(uint2*)(prow + ((g * 8 + 32) ^ X)) = w1;
    }
    short8 pf[4];
#pragma unroll
    for (int qf = 0; qf < 4; ++qf)
      pf[qf] = *(const short8*)(pw + (qf * 16 + i) * 64 + ((g * 16) ^ X));
    __builtin_amdgcn_s_setprio(1);
#pragma unroll
    for (int df = 0; df < 4; ++df) {
      const int d = df * 16 + i;
      short8 vf = *(const short8*)((const char*)VTl + d * 512 + ((c * 64 + g * 16) ^ ((d & 7) << 4)));
#pragma unroll
      for (int qf = 0; qf < 4; ++qf)
        o[df][qf] = __builtin_amdgcn_mfma_f32_16x16x32_bf16(vf, pf[qf], o[df][qf], 0, 0, 0);
    }
    __builtin_amdgcn_s_setprio(0);
  }

#pragma unroll
  for (int qf = 0; qf < 4; ++qf) {
    l[qf] += __shfl_xor(l[qf], 16);
    l[qf] += __shfl_xor(l[qf], 32);
  }

  const long b = bh / 12;
  const int hh = (int)(bh % 12);
#pragma unroll
  for (int qf = 0; qf < 4; ++qf) {
    const float inv = 1.f / l[qf];
    const long q = w * 64 + qf * 16 + i;
    u16* op = out + (b * 256 + q) * 768 + hh * 64;
#pragma unroll
    for (int df = 0; df < 4; ++df) {
      const int d0 = df * 16 + g * 4;
      unsigned int a = (unsigned int)f2bf(o[df][qf][0] * inv) | ((unsigned int)f2bf(o[df][qf][1] * inv) << 16);
      unsigned int bb = (unsigned int)f2bf(o[df][qf][2] * inv) | ((unsigned int)f2bf(o[df][qf][3] * inv) << 16);
      *(unsigned int*)(op + d0) = a;
      *(unsigned int*)(op + d0 + 2) = bb;
    }
  }
}

// ---------------- pixel shuffle + 3x3 SAME conv + bias, LDS-tiled.
__global__ __launch_bounds__(256) void conv_out_kernel(const float* __restrict__ y, const float* __restrict__ w,
                                                       const float* __restrict__ cb, float* __restrict__ out) {
  __shared__ float buf[18 * 258 * 3];
  __shared__ float wl[81];
  __shared__ float cbl[3];
  const int tid = threadIdx.x;
  const int gh = blockIdx.x;
  const long b = blockIdx.y;
  for (int idx = tid; idx < 18 * 258 * 3; idx += 256) buf[idx] = 0.f;
  if (tid < 81) wl[tid] = w[tid];
  if (tid < 3) cbl[tid] = cb[tid];
  __syncthreads();
  const float* yb = y + (b * 256 + gh * 16) * 768;
  for (int idx = tid; idx < 12288; idx += 256) {
    const int gw = idx / 768, col = idx - gw * 768;
    const int ph = col / 48, rem = col - ph * 48;
    const int pw = rem / 3, ii = rem - pw * 3;
    buf[((ph + 1) * 258 + gw * 16 + pw + 1) * 3 + ii] = yb[idx];
  }
  if (gh > 0) {
    const float* yh = y + (b * 256 + (gh - 1) * 16) * 768;
    for (int idx = tid; idx < 768; idx += 256) {
      const int gw = idx / 48, rem = idx - gw * 48;
      const int pw = rem / 3, ii = rem - pw * 3;
      buf[(gw * 16 + pw + 1) * 3 + ii] = yh[gw * 768 + 720 + rem];
    }
  }
  if (gh < 15) {
    const float* yh = y + (b * 256 + (gh + 1) * 16) * 768;
    for (int idx = tid; idx < 768; idx += 256) {
      const int gw = idx / 48, rem = idx - gw * 48;
      const int pw = rem / 3, ii = rem - pw * 3;
      buf[(17 * 258 + gw * 16 + pw + 1) * 3 + ii] = yh[gw * 768 + rem];
    }
  }
  __syncthreads();
  const int c = tid;
  for (int rl = 0; rl < 16; ++rl) {
    float a0 = cbl[0], a1 = cbl[1], a2 = cbl[2];
#pragma unroll
    for (int ky = 0; ky < 3; ++ky)
#pragma unroll
      for (int kx = 0; kx < 3; ++kx)
#pragma unroll
        for (int ii = 0; ii < 3; ++ii) {
          const float v = buf[((rl + ky) * 258 + c + kx) * 3 + ii];
          const int wi = ii * 9 + ky * 3 + kx;
          a0 += v * wl[wi];
          a1 += v * wl[27 + wi];
          a2 += v * wl[54 + wi];
        }
    const long r = gh * 16 + rl;
    out[((b * 3 + 0) * 256 + r) * 256 + c] = a0;
    out[((b * 3 + 1) * 256 + r) * 256 + c] = a1;
    out[((b * 3 + 2) * 256 + r) * 256 + c] = a2;
  }
}

extern "C" void kernel_launch(void* const* d_in, const int* in_sizes, int n_in,
                              void* d_out, int out_size, void* d_ws, size_t ws_size,
                              hipStream_t stream) {
  const float* z_latents = (const float*)d_in[0];
  const float* pos_emb   = (const float*)d_in[1];
  const float* W_embed   = (const float*)d_in[2];
  const float* b_embed   = (const float*)d_in[3];
  const float* ln_pre_w  = (const float*)d_in[4];
  const float* n1_w      = (const float*)d_in[5];
  const float* qkv_w     = (const float*)d_in[6];
  const float* qkv_b     = (const float*)d_in[7];
  const float* proj_w    = (const float*)d_in[8];
  const float* proj_b    = (const float*)d_in[9];
  const float* n2_w      = (const float*)d_in[10];
  const float* w12_w     = (const float*)d_in[11];
  const float* w12_b     = (const float*)d_in[12];
  const float* w3_w      = (const float*)d_in[13];
  const float* w3_b      = (const float*)d_in[14];
  const float* ln_post_w = (const float*)d_in[15];
  const float* conv1_w   = (const float*)d_in[16];
  const float* conv1_b   = (const float*)d_in[17];
  const float* conv_ow   = (const float*)d_in[18];
  const float* conv_ob   = (const float*)d_in[19];
  const float* rope      = (const float*)d_in[20];

  if (ws_size < 598867968ULL) return;
  char* p = (char*)d_ws;
  auto alloc = [&](size_t bytes) { char* r = p; p += (bytes + 255) & ~(size_t)255; return r; };
  float* z    = (float*)alloc(16384L * 768 * 4);
  u16*   h    = (u16*)alloc(16384L * 768 * 2);
  u16*   big  = (u16*)alloc(16384L * 4096 * 2);  // unused (layout stability)
  u16*   q_r  = (u16*)alloc(16384L * 768 * 2);
  u16*   k_s  = (u16*)alloc(16384L * 768 * 2);
  u16*   v_t  = (u16*)alloc(16384L * 768 * 2);
  u16*   ao   = (u16*)alloc(16384L * 768 * 2);
  u16*   u    = (u16*)alloc(16384L * 2048 * 2);
  float* y    = (float*)alloc(16384L * 768 * 4);
  u16* qkvT   = (u16*)alloc(12L * 2304 * 768 * 2);
  u16* projT  = (u16*)alloc(12L * 768 * 768 * 2);
  u16* w12T   = (u16*)alloc(12L * 4096 * 768 * 2);
  u16* w3T    = (u16*)alloc(12L * 768 * 2048 * 2);
  u16* c1T    = (u16*)alloc(768L * 768 * 2);
  (void)big;

  const dim3 tb(32, 8);
  transpose_conv<<<dim3(72, 24, 12), tb, 0, stream>>>(qkv_w, qkvT, 768, 2304, 0);
  transpose_conv<<<dim3(24, 24, 12), tb, 0, stream>>>(proj_w, projT, 768, 768, 0);
  transpose_conv<<<dim3(128, 24, 12), tb, 0, stream>>>(w12_w, w12T, 768, 4096, 2);  // 32-granular x1/x2
  transpose_conv<<<dim3(24, 64, 12), tb, 0, stream>>>(w3_w, w3T, 2048, 768, 0);
  transpose_conv<<<dim3(24, 24, 1), tb, 0, stream>>>(conv1_w, c1T, 768, 768, 0);

  embed_kernel<<<16384, 256, 0, stream>>>(z_latents, pos_emb, W_embed, b_embed, ln_pre_w, z);

  for (int l = 0; l < 12; ++l) {
    rms_wave<<<512, 256, 0, stream>>>(z, n1_w + l * 768, h);
    gemm128s<4><<<2304, 256, 0, stream>>>(h, qkvT + (long)l * 2304 * 768, nullptr,
                                          qkv_b + l * 2304, 16384, 2304, 768, 18, 6,
                                          rope, q_r, k_s, v_t);
    attn_kernel<<<768, 256, 0, stream>>>(q_r, k_s, v_t, ao);
    gemm128s<2><<<768, 256, 0, stream>>>(ao, projT + (long)l * 768 * 768, z,
                                         proj_b + l * 768, 16384, 768, 768, 6, 0,
                                         nullptr, nullptr, nullptr, nullptr);
    rms_wave<<<512, 256, 0, stream>>>(z, n2_w + l * 768, h);
    gemm128s<3><<<4096, 256, 0, stream>>>(h, w12T + (long)l * 4096 * 768, u,
                                          w12_b + l * 4096, 16384, 4096, 768, 32, 16,
                                          nullptr, nullptr, nullptr, nullptr);
    gemm128s<2><<<768, 256, 0, stream>>>(u, w3T + (long)l * 768 * 2048, z,
                                         w3_b + l * 768, 16384, 768, 2048, 6, 0,
                                         nullptr, nullptr, nullptr, nullptr);
  }

  rms_wave<<<512, 256, 0, stream>>>(z, ln_post_w, h);
  gemm128s<0><<<768, 256, 0, stream>>>(h, c1T, y, conv1_b, 16384, 768, 768, 6, 0,
                                       nullptr, nullptr, nullptr, nullptr);
  conv_out_kernel<<<dim3(16, 64), 256, 0, stream>>>(y, conv_ow, conv_ob, (float*)d_out);
}